// Round 19
// baseline (3353.416 us; speedup 1.0000x reference)
//
#include <hip/hip_runtime.h>
#include <hip/hip_bf16.h>
#include <cstdint>
#include <cstddef>

constexpr int NB = 8;      // batch
constexpr int NP = 2048;   // points per cloud
constexpr int BN = NB * NP;  // 16384
constexpr int KK = 20;     // neighbors
constexpr float EPSBN = 1e-5f;
constexpr float NEG = -3.402823466e38f;
constexpr int SLOTS = 8;    // fp32 conv1 stats slots
constexpr int SLOTSM = 32;  // gmax stats slots
constexpr int SLOTSW = 8;   // w5 stats slots

typedef __attribute__((ext_vector_type(8))) short bf16x8;   // 8 bf16 = 4 VGPRs
typedef __attribute__((ext_vector_type(16))) float f32x16;  // 32x32 MFMA acc

__device__ __forceinline__ float leaky(float x) { return x > 0.f ? x : 0.2f * x; }

__device__ __forceinline__ void split2(float x, unsigned short& h, unsigned short& l) {
    __hip_bfloat16 hh = __float2bfloat16(x);
    float hf = __bfloat162float(hh);
    __hip_bfloat16 ll = __float2bfloat16(x - hf);
    h = *reinterpret_cast<unsigned short*>(&hh);
    l = *reinterpret_cast<unsigned short*>(&ll);
}

__device__ __forceinline__ float b2f(unsigned short u) {
    __hip_bfloat16 h = *reinterpret_cast<__hip_bfloat16*>(&u);
    return __bfloat162float(h);
}

// float -> orderable u32 (ascending uint == ascending float)
__device__ __forceinline__ unsigned int f2key(float f) {
    unsigned int u = __float_as_uint(f);
    return u ^ (unsigned int)(((int)u >> 31) | 0x80000000);
}

// ---------------- transpose x [8,3,2048] -> xt [BN][4] (pad c3=0); xt doubles as FT4 (CP4=1)
__global__ void k_transpose(const float* __restrict__ x, float* __restrict__ xt) {
    int i = blockIdx.x * 256 + threadIdx.x;
    if (i >= BN) return;
    int b = i >> 11, n = i & 2047;
    float4 v;
    v.x = x[(b * 3 + 0) * NP + n];
    v.y = x[(b * 3 + 1) * NP + n];
    v.z = x[(b * 3 + 2) * NP + n];
    v.w = 0.f;
    *(float4*)&xt[(size_t)i * 4] = v;
}

// ---------------- sq from quad-packed FT4 [CP4][BN]
template <int CP4>
__global__ void k_sq4(const float4* __restrict__ FT4, float* __restrict__ sq) {
    int i = blockIdx.x * 256 + threadIdx.x;
    if (i >= BN) return;
    float s = 0.f;
#pragma unroll
    for (int cq = 0; cq < CP4; ++cq) {
        float4 f = FT4[(size_t)cq * BN + i];
        s += f.x * f.x + f.y * f.y + f.z * f.z + f.w * f.w;
    }
    sq[i] = s;
}

// ---------------- knn half-tile: 8 center rows x 1024 m (half), 512 threads,
// 32 KiB LDS keys -> 4 blocks/CU (32 waves). Per-half top-20 -> candidates.
// fp32 FMA order identical to prior rounds -> bit-identical keys.
template <int CP>
__launch_bounds__(512, 8)
__global__ void k_knn3(const float4* __restrict__ FT4, const float* __restrict__ sq,
                       unsigned int* __restrict__ ckey, int* __restrict__ cidx) {
    constexpr int R = 8;
    constexpr int CP4 = CP / 4;
    constexpr int HM = 1024;             // half of NP
    __shared__ unsigned int ds[R][HM];   // 32 KiB of keys
    int t = threadIdx.x;
    int bx = blockIdx.x;
    int b = bx >> 9;                     // 512 blocks per batch (256 tiles x 2 halves)
    int rest = bx & 511;
    int half = rest & 1;
    int n0 = (rest >> 1) * R;
    int mbase = half * HM;
    const float4* FTb = FT4 + (size_t)b * NP;
    const float* sqb = sq + (size_t)b * NP;

    float acc[R][2];
#pragma unroll
    for (int r = 0; r < R; ++r) { acc[r][0] = 0.f; acc[r][1] = 0.f; }

    for (int cq = 0; cq < CP4; ++cq) {
        float4 f0 = FTb[(size_t)cq * BN + mbase + t];
        float4 f1 = FTb[(size_t)cq * BN + mbase + t + 512];
#pragma unroll
        for (int r = 0; r < R; ++r) {
            float4 cv = FTb[(size_t)cq * BN + n0 + r];
            acc[r][0] += f0.x * cv.x + f0.y * cv.y + f0.z * cv.z + f0.w * cv.w;
            acc[r][1] += f1.x * cv.x + f1.y * cv.y + f1.z * cv.z + f1.w * cv.w;
        }
    }
    {
        float sm0 = sqb[mbase + t];
        float sm1 = sqb[mbase + t + 512];
#pragma unroll
        for (int r = 0; r < R; ++r) {
            ds[r][t] = f2key(sm0 - 2.f * acc[r][0]);
            ds[r][t + 512] = f2key(sm1 - 2.f * acc[r][1]);
        }
    }
    __syncthreads();

    // selection: 8 waves, wave handles row `wave`; 16 chunks cover 1024 m
    int wave = t >> 6, lane = t & 63;
    unsigned long long below = (1ull << lane) - 1ull;
    {
        int r = wave;
        unsigned int kv[16];
#pragma unroll
        for (int j = 0; j < 16; ++j) kv[j] = ds[r][lane + 64 * j];

        unsigned int T = 0;
#pragma unroll 1
        for (int bit = 31; bit >= 0; --bit) {
            unsigned int tt = T | (1u << bit);
            int c = 0;
#pragma unroll
            for (int j = 0; j < 16; ++j)
                c += (int)__popcll(__ballot(kv[j] >= tt));
            if (c >= KK) T = tt;
        }

        int cb = ((b * NP + n0 + r) * 2 + half) * KK;
        int base = 0;
#pragma unroll 1
        for (int j = 0; j < 16; ++j) {
            bool pg = kv[j] > T;
            unsigned long long mk = __ballot(pg);
            if (pg) {
                int pos = base + (int)__popcll(mk & below);
                ckey[cb + pos] = kv[j];
                cidx[cb + pos] = mbase + lane + 64 * j;
            }
            base += (int)__popcll(mk);
        }
        int rem = KK - base;
#pragma unroll 1
        for (int j = 0; j < 16; ++j) {
            if (rem <= 0) break;
            bool pe = kv[j] == T;
            unsigned long long mk = __ballot(pe);
            int myp = (int)__popcll(mk & below);
            if (pe && myp < rem) {
                ckey[cb + base + myp] = kv[j];
                cidx[cb + base + myp] = mbase + lane + 64 * j;
            }
            int cnt = (int)__popcll(mk);
            int take = cnt < rem ? cnt : rem;
            base += take; rem -= take;
        }
    }
}

// ---------------- merge the two half top-20s into global top-20 (exact set,
// (key desc, idx asc) rule == jax top_k on farthest-distance keys)
__global__ void k_kmerge(const unsigned int* __restrict__ ckey, const int* __restrict__ cidx,
                         int* __restrict__ gidx) {
    int p = blockIdx.x * 256 + threadIdx.x;
    if (p >= BN) return;
    unsigned long long pk[40];
#pragma unroll
    for (int j = 0; j < 40; ++j) {
        unsigned long long k = ckey[(size_t)p * 40 + j];
        int gi = cidx[(size_t)p * 40 + j];
        pk[j] = (k << 32) | (unsigned int)(2047 - gi);
    }
    unsigned long long used = 0;
#pragma unroll 1
    for (int it = 0; it < KK; ++it) {
        unsigned long long bv = 0; int bj = 0;
#pragma unroll
        for (int j = 0; j < 40; ++j) {
            unsigned long long v = ((used >> j) & 1ull) ? 0ull : pk[j];
            if (v > bv) { bv = v; bj = j; }
        }
        used |= 1ull << bj;
        gidx[(size_t)p * KK + it] = 2047 - (int)(bv & 0xffffffffu);
    }
}

// ---------------- prep (conv1, fp32): W [O][2C] -> WaT [CP][O], WdT [CP][O]
__global__ void k_prepw(const float* __restrict__ W, int O, int Cact, int CP,
                        float* __restrict__ WaT, float* __restrict__ WdT) {
    int i = blockIdx.x * 256 + threadIdx.x;
    if (i >= CP * O) return;
    int c = i / O, o = i % O;
    float wa = (c < Cact) ? W[o * 2 * Cact + c] : 0.f;
    float wb = (c < Cact) ? W[o * 2 * Cact + Cact + c] : 0.f;
    WaT[i] = wa;
    WdT[i] = wb - wa;
}

// ---------------- prep combined: W [O][2C] fp32 -> Wcmb [2O][C] split h/l
__global__ void k_prepws2(const float* __restrict__ W, int O, int C,
                          unsigned short* __restrict__ WcH, unsigned short* __restrict__ WcL) {
    int i = blockIdx.x * 256 + threadIdx.x;
    if (i >= 2 * O * C) return;
    int r = i / C, k = i % C;
    float v;
    if (r < O) v = W[r * 2 * C + k];
    else {
        int o = r - O;
        v = W[o * 2 * C + C + k] - W[o * 2 * C + k];
    }
    split2(v, WcH[i], WcL[i]);
}

// ---------------- split w5 [1024][512] fp32 -> hi/lo bf16
__global__ void k_splitw5(const float* __restrict__ w5, unsigned short* __restrict__ w5H,
                          unsigned short* __restrict__ w5L) {
    int i = blockIdx.x * 256 + threadIdx.x;
    if (i >= 1024 * 512) return;
    split2(w5[i], w5H[i], w5L[i]);
}

// ---------------- fp32 edge conv (layer 1 only, tiny C)
template <int O, int CP>
__launch_bounds__(O)
__global__ void k_conv(const float* __restrict__ F, int ld, const int* __restrict__ gidx,
                       const float* __restrict__ WaT, const float* __restrict__ WdT,
                       float* __restrict__ hmax, float* __restrict__ s1p,
                       float* __restrict__ s2p) {
    constexpr int CP4 = CP / 4;
    __shared__ float nbrT[2][CP][32];
    __shared__ float sctr[2][CP];
    __shared__ int sidx[2][KK];
    int t = threadIdx.x;
    int p0 = blockIdx.x * 2;
    int b = p0 >> 11;
    const float* Fb = F + (size_t)b * NP * ld;

    if (t < 2 * KK) {
        int pt = t / KK, k = t % KK;
        sidx[pt][k] = gidx[(size_t)(p0 + pt) * KK + k];
    }
    for (int e = t; e < 2 * CP; e += O) {
        int pt = e / CP, cc = e % CP;
        int n = (p0 + pt) & 2047;
        sctr[pt][cc] = Fb[(size_t)n * ld + cc];
    }
    __syncthreads();
    for (int e = t; e < 2 * KK * CP4; e += O) {
        int pt = e / (KK * CP4);
        int e2 = e % (KK * CP4);
        int k = e2 / CP4, cq = e2 % CP4;
        float4 f = *(const float4*)&Fb[(size_t)sidx[pt][k] * ld + cq * 4];
        int kp = (k + 4 * (cq & 7)) & 31;
        nbrT[pt][cq * 4 + 0][kp] = f.x;
        nbrT[pt][cq * 4 + 1][kp] = f.y;
        nbrT[pt][cq * 4 + 2][kp] = f.z;
        nbrT[pt][cq * 4 + 3][kp] = f.w;
    }
    __syncthreads();

    int o = t;
    float bacc0 = 0.f, bacc1 = 0.f;
#pragma unroll 4
    for (int c = 0; c < CP; ++c) {
        float w = WdT[c * O + o];
        bacc0 += sctr[0][c] * w;
        bacc1 += sctr[1][c] * w;
    }
    float a0[KK], a1[KK];
#pragma unroll
    for (int k = 0; k < KK; ++k) { a0[k] = 0.f; a1[k] = 0.f; }
#pragma unroll 2
    for (int c = 0; c < CP; ++c) {
        float w = WaT[c * O + o];
        int s = 4 * ((c >> 2) & 7);
#pragma unroll
        for (int kq = 0; kq < KK / 4; ++kq) {
            int kp = (4 * kq + s) & 31;
            float4 f0 = *(const float4*)&nbrT[0][c][kp];
            float4 f1 = *(const float4*)&nbrT[1][c][kp];
            a0[kq * 4 + 0] += w * f0.x; a1[kq * 4 + 0] += w * f1.x;
            a0[kq * 4 + 1] += w * f0.y; a1[kq * 4 + 1] += w * f1.y;
            a0[kq * 4 + 2] += w * f0.z; a1[kq * 4 + 2] += w * f1.z;
            a0[kq * 4 + 3] += w * f0.w; a1[kq * 4 + 3] += w * f1.w;
        }
    }
    float hm0 = NEG, hm1 = NEG, ts1 = 0.f, ts2 = 0.f;
#pragma unroll
    for (int k = 0; k < KK; ++k) {
        float h0 = a0[k] + bacc0;
        float h1 = a1[k] + bacc1;
        hm0 = fmaxf(hm0, h0); hm1 = fmaxf(hm1, h1);
        ts1 += h0 + h1; ts2 += h0 * h0 + h1 * h1;
    }
    hmax[(size_t)p0 * O + o] = hm0;
    hmax[(size_t)(p0 + 1) * O + o] = hm1;
    int slot = blockIdx.x & (SLOTS - 1);
    atomicAdd(&s1p[slot * O + o], ts1);
    atomicAdd(&s2p[slot * O + o], ts2);
}

// ---------------- dense split GEMM: Gz[BN][O] = hc[:, COFF:COFF+C] @ Wcmb^T (fp32 out)
template <int O, int C, int COFF>
__launch_bounds__(256, 4)
__global__ void k_gemms(const unsigned short* __restrict__ hcH,
                        const unsigned short* __restrict__ hcL,
                        const unsigned short* __restrict__ WdH,
                        const unsigned short* __restrict__ WdL,
                        float* __restrict__ bacc) {
    constexpr int KS = C / 16;
    int tid = threadIdx.x, wave = tid >> 6, lane = tid & 63;
    int row = lane & 31, half = lane >> 5;
    int p0 = blockIdx.x * 128 + wave * 32;
    int ob = blockIdx.y * 64;
    const unsigned short* aH = hcH + (size_t)(p0 + row) * 512 + COFF;
    const unsigned short* aL = hcL + (size_t)(p0 + row) * 512 + COFF;
    f32x16 acc[2];
#pragma unroll
    for (int nt = 0; nt < 2; ++nt)
#pragma unroll
        for (int r = 0; r < 16; ++r) acc[nt][r] = 0.f;

#pragma unroll 2
    for (int ks = 0; ks < KS; ++ks) {
        int k0 = ks * 16 + half * 8;
        bf16x8 avh = *(const bf16x8*)(aH + k0);
        bf16x8 avl = *(const bf16x8*)(aL + k0);
#pragma unroll
        for (int nt = 0; nt < 2; ++nt) {
            int j = ob + nt * 32 + row;
            bf16x8 bvh = *(const bf16x8*)(WdH + (size_t)j * C + k0);
            bf16x8 bvl = *(const bf16x8*)(WdL + (size_t)j * C + k0);
            acc[nt] = __builtin_amdgcn_mfma_f32_32x32x16_bf16(avh, bvh, acc[nt], 0, 0, 0);
            acc[nt] = __builtin_amdgcn_mfma_f32_32x32x16_bf16(avh, bvl, acc[nt], 0, 0, 0);
            acc[nt] = __builtin_amdgcn_mfma_f32_32x32x16_bf16(avl, bvh, acc[nt], 0, 0, 0);
        }
    }
#pragma unroll
    for (int nt = 0; nt < 2; ++nt)
#pragma unroll
        for (int r = 0; r < 16; ++r) {
            int i = (r & 3) + 8 * (r >> 2) + 4 * half;
            bacc[(size_t)(p0 + i) * O + ob + nt * 32 + row] = acc[nt][r];
        }
}

// ---------------- gather-max epilogue: hmax[p,o] = max_k Gz[nbr_k, o] + bacc
template <int O>
__launch_bounds__(256)
__global__ void k_gmax(const float* __restrict__ Gz, const int* __restrict__ gidx,
                       float* __restrict__ hmax, float* __restrict__ s1p,
                       float* __restrict__ s2p) {
    constexpr int PB = 256 / O;      // points per block
    constexpr int O2 = 2 * O;
    __shared__ int sidx[PB][KK];
    int t = threadIdx.x;
    int pt = t / O, o = t % O;
    int p0 = blockIdx.x * PB;
    if (t < PB * KK) sidx[t / KK][t % KK] = gidx[(size_t)(p0 + t / KK) * KK + t % KK];
    __syncthreads();

    int p = p0 + pt;
    int b = p >> 11;
    const float* Gb = Gz + (size_t)b * 2048 * O2;
    float bacc = Gz[(size_t)p * O2 + O + o];
    float mx = NEG, ts1 = 0.f, ts2 = 0.f;
#pragma unroll 5
    for (int k = 0; k < KK; ++k) {
        float g = Gb[(size_t)sidx[pt][k] * O2 + o];
        float h = g + bacc;
        mx = fmaxf(mx, g);
        ts1 += h; ts2 += h * h;
    }
    hmax[(size_t)p * O + o] = mx + bacc;
    int slot = blockIdx.x & (SLOTSM - 1);
    atomicAdd(&s1p[slot * O + o], ts1);
    atomicAdd(&s2p[slot * O + o], ts2);
}

// ---------------- reduce slotted stats -> s1g/s2g
__global__ void k_redslots(const float* __restrict__ s1p, const float* __restrict__ s2p,
                           int O, int S, float* __restrict__ s1g, float* __restrict__ s2g) {
    int o = blockIdx.x * 256 + threadIdx.x;
    if (o >= O) return;
    float a = 0.f, c = 0.f;
    for (int s = 0; s < S; ++s) { a += s1p[s * O + o]; c += s2p[s * O + o]; }
    s1g[o] = a; s2g[o] = c;
}

// ---------------- BN(+leaky) on per-point max; writes split hi/lo bf16
__global__ void k_bnmax(const float* __restrict__ hmax, int O, const float* __restrict__ s1g,
                        const float* __restrict__ s2g, const float* __restrict__ gam,
                        const float* __restrict__ bet, unsigned short* __restrict__ outH,
                        unsigned short* __restrict__ outL, int ostride, int ooff,
                        float inv_cnt) {
    int i = blockIdx.x * 256 + threadIdx.x;
    if (i >= BN * O) return;
    int o = i % O, p = i / O;
    float m = s1g[o] * inv_cnt;
    float v = s2g[o] * inv_cnt - m * m;
    float rs = rsqrtf(v + EPSBN);
    float y = leaky(gam[o] * (hmax[i] - m) * rs + bet[o]);
    size_t oi = (size_t)p * ostride + ooff + o;
    split2(y, outH[oi], outL[oi]);
}

// ---------------- pack: hi/lo bf16 cols [coff+o0,...) -> quad-packed FT4 [CP4][BN]
__global__ void k_pack4(const unsigned short* __restrict__ inH,
                        const unsigned short* __restrict__ inL, int coff,
                        float4* __restrict__ out) {
    __shared__ float tile[64][65];
    int tx = threadIdx.x & 63, ty = threadIdx.x >> 6;
    int p0 = blockIdx.x * 64, o0 = blockIdx.y * 64;
    for (int i = ty; i < 64; i += 4) {
        size_t idx = (size_t)(p0 + i) * 512 + coff + o0 + tx;
        tile[i][tx] = b2f(inH[idx]) + b2f(inL[idx]);
    }
    __syncthreads();
    for (int q = ty; q < 16; q += 4) {
        float4 v;
        v.x = tile[tx][4 * q + 0];
        v.y = tile[tx][4 * q + 1];
        v.z = tile[tx][4 * q + 2];
        v.w = tile[tx][4 * q + 3];
        out[(size_t)(o0 / 4 + q) * BN + p0 + tx] = v;
    }
}

// ---------------- w5 split GEMM: g5 = hc[BN][512] @ w5^T -> fp32 [BN][1024] + stats
// NT=4 (wave covers 128 cols), grid.y = 2.
__launch_bounds__(256, 3)
__global__ void k_w5ms(const unsigned short* __restrict__ hcH,
                       const unsigned short* __restrict__ hcL,
                       const unsigned short* __restrict__ w5H,
                       const unsigned short* __restrict__ w5L,
                       float* __restrict__ g5, float* __restrict__ s1p,
                       float* __restrict__ s2p) {
    int tid = threadIdx.x, wave = tid >> 6, lane = tid & 63;
    int row = lane & 31, half = lane >> 5;
    int p0 = blockIdx.x * 32;
    int ob = blockIdx.y * 512 + wave * 128;
    const unsigned short* aH = hcH + (size_t)(p0 + row) * 512;
    const unsigned short* aL = hcL + (size_t)(p0 + row) * 512;
    f32x16 acc[4];
#pragma unroll
    for (int nt = 0; nt < 4; ++nt)
#pragma unroll
        for (int r = 0; r < 16; ++r) acc[nt][r] = 0.f;

#pragma unroll 2
    for (int ks = 0; ks < 32; ++ks) {
        int k0 = ks * 16 + half * 8;
        bf16x8 avh = *(const bf16x8*)(aH + k0);
        bf16x8 avl = *(const bf16x8*)(aL + k0);
#pragma unroll
        for (int nt = 0; nt < 4; ++nt) {
            int j = ob + nt * 32 + row;
            bf16x8 bvh = *(const bf16x8*)(w5H + (size_t)j * 512 + k0);
            bf16x8 bvl = *(const bf16x8*)(w5L + (size_t)j * 512 + k0);
            acc[nt] = __builtin_amdgcn_mfma_f32_32x32x16_bf16(avh, bvh, acc[nt], 0, 0, 0);
            acc[nt] = __builtin_amdgcn_mfma_f32_32x32x16_bf16(avh, bvl, acc[nt], 0, 0, 0);
            acc[nt] = __builtin_amdgcn_mfma_f32_32x32x16_bf16(avl, bvh, acc[nt], 0, 0, 0);
        }
    }
    int slot = blockIdx.x & (SLOTSW - 1);
#pragma unroll
    for (int nt = 0; nt < 4; ++nt) {
        int j = ob + nt * 32 + row;
        float s1 = 0.f, s2 = 0.f;
#pragma unroll
        for (int r = 0; r < 16; ++r) {
            int i = (r & 3) + 8 * (r >> 2) + 4 * half;
            float v = acc[nt][r];
            g5[(size_t)(p0 + i) * 1024 + j] = v;
            s1 += v; s2 += v * v;
        }
        s1 += __shfl_xor(s1, 32);
        s2 += __shfl_xor(s2, 32);
        if (half == 0) {
            atomicAdd(&s1p[slot * 1024 + j], s1);
            atomicAdd(&s2p[slot * 1024 + j], s2);
        }
    }
}

// ---------------- pool: per (b, o-tile, n-chunk) partial max / partial sum
__global__ void k_pool(const float* __restrict__ gbuf, const float* __restrict__ s1g,
                       const float* __restrict__ s2g, const float* __restrict__ gam,
                       const float* __restrict__ bet, float* __restrict__ pmax,
                       float* __restrict__ psum) {
    int t = threadIdx.x;
    int blk = blockIdx.x;
    int nc = blk & 7, ot = (blk >> 3) & 3, b = blk >> 5;
    int o = ot * 256 + t;
    float m = s1g[o] * (1.f / 16384.f);
    float v = s2g[o] * (1.f / 16384.f) - m * m;
    float rs = rsqrtf(v + EPSBN);
    float ga = gam[o], be = bet[o];
    float vmax = NEG, vsum = 0.f;
    for (int j = 0; j < 256; ++j) {
        int n = nc * 256 + j;
        float x = gbuf[((size_t)b * NP + n) * 1024 + o];
        float y = leaky(ga * (x - m) * rs + be);
        vmax = fmaxf(vmax, y);
        vsum += y;
    }
    pmax[(b * 1024 + o) * 8 + nc] = vmax;
    psum[(b * 1024 + o) * 8 + nc] = vsum;
}

__global__ void k_poolfin(const float* __restrict__ pmax, const float* __restrict__ psum,
                          float* __restrict__ pooled) {
    int i = blockIdx.x * 256 + threadIdx.x;
    if (i >= 8192) return;
    float mx = NEG, sm = 0.f;
    for (int j = 0; j < 8; ++j) {
        mx = fmaxf(mx, pmax[i * 8 + j]);
        sm += psum[i * 8 + j];
    }
    int b = i >> 10, o = i & 1023;
    pooled[b * 2048 + o] = mx;
    pooled[b * 2048 + 1024 + o] = sm * (1.f / 2048.f);
}

// ---------------- small FC: z[b][o] = in[b] . W[o] (+bias)
template <int CIN>
__global__ void k_fc(const float* __restrict__ in, const float* __restrict__ W,
                     const float* __restrict__ bias, int O, float* __restrict__ z) {
    int i = blockIdx.x * 256 + threadIdx.x;
    if (i >= NB * O) return;
    int b = i / O, o = i % O;
    const float* wr = W + (size_t)o * CIN;
    const float* ir = in + (size_t)b * CIN;
    float acc = 0.f;
#pragma unroll 4
    for (int cq = 0; cq < CIN / 4; ++cq) {
        float4 wv = *(const float4*)&wr[cq * 4];
        float4 iv = *(const float4*)&ir[cq * 4];
        acc += wv.x * iv.x + wv.y * iv.y + wv.z * iv.z + wv.w * iv.w;
    }
    z[i] = acc + (bias ? bias[o] : 0.f);
}

// ---------------- BN over batch (8 samples) + leaky
__global__ void k_bnb(const float* __restrict__ z, int O, const float* __restrict__ gam,
                      const float* __restrict__ bet, float* __restrict__ out, int ostride,
                      int ooff) {
    int o = blockIdx.x * 256 + threadIdx.x;
    if (o >= O) return;
    float s1 = 0.f, s2 = 0.f;
#pragma unroll
    for (int b = 0; b < NB; ++b) {
        float x = z[b * O + o];
        s1 += x; s2 += x * x;
    }
    float m = s1 * 0.125f, v = s2 * 0.125f - m * m;
    float rs = rsqrtf(v + EPSBN);
    float ga = gam[o], be = bet[o];
    for (int b = 0; b < NB; ++b) {
        float y = ga * (z[b * O + o] - m) * rs + be;
        out[b * ostride + ooff + o] = leaky(y);
    }
}

// ---------------- head
__global__ void k_head(const float* __restrict__ hf, const float* __restrict__ wh,
                       const float* __restrict__ bh, const float* __restrict__ g8,
                       const float* __restrict__ b8, float* __restrict__ out) {
    __shared__ float zh[56];
    int t = threadIdx.x;
    if (t < 56) {
        int b = t / 7, o = t % 7;
        float acc = bh[o];
        for (int c = 0; c < 768; ++c) acc += hf[b * 768 + c] * wh[o * 768 + c];
        zh[t] = acc;
    }
    __syncthreads();
    if (t < 7) {
        float s1 = 0.f, s2 = 0.f;
        for (int b = 0; b < NB; ++b) {
            float x = zh[b * 7 + t];
            s1 += x; s2 += x * x;
        }
        float m = s1 * 0.125f, v = s2 * 0.125f - m * m;
        float rs = rsqrtf(v + EPSBN);
        for (int b = 0; b < NB; ++b) {
            float y = g8[t] * (zh[b * 7 + t] - m) * rs + b8[t];
            out[b * 7 + t] = fmaxf(y, 0.f);
        }
    }
}

extern "C" void kernel_launch(void* const* d_in, const int* in_sizes, int n_in, void* d_out,
                              int out_size, void* d_ws, size_t ws_size, hipStream_t stream) {
    const float* x[3] = {(const float*)d_in[0], (const float*)d_in[1], (const float*)d_in[2]};
    const float* w1 = (const float*)d_in[3];
    const float* w2 = (const float*)d_in[4];
    const float* w3 = (const float*)d_in[5];
    const float* w4 = (const float*)d_in[6];
    const float* w5 = (const float*)d_in[7];
    const float* wl1 = (const float*)d_in[8];
    const float* wl2 = (const float*)d_in[9];
    const float* bl2 = (const float*)d_in[10];
    const float* whead = (const float*)d_in[11];
    const float* bhead = (const float*)d_in[12];
    const float *g1 = (const float*)d_in[13], *b1 = (const float*)d_in[14];
    const float *g2 = (const float*)d_in[15], *b2 = (const float*)d_in[16];
    const float *g3 = (const float*)d_in[17], *b3 = (const float*)d_in[18];
    const float *g4 = (const float*)d_in[19], *b4 = (const float*)d_in[20];
    const float *g5 = (const float*)d_in[21], *b5 = (const float*)d_in[22];
    const float *g6 = (const float*)d_in[23], *b6 = (const float*)d_in[24];
    const float *g7 = (const float*)d_in[25], *b7 = (const float*)d_in[26];
    const float *g8 = (const float*)d_in[27], *b8 = (const float*)d_in[28];

    char* w = (char*)d_ws;
    auto alloc = [&](size_t bytes) {
        char* p = w;
        w += (bytes + 255) & ~(size_t)255;
        return p;
    };
    float* xt   = (float*)alloc((size_t)BN * 4 * 4);
    unsigned short* hcH = (unsigned short*)alloc((size_t)BN * 512 * 2);
    unsigned short* hcL = (unsigned short*)alloc((size_t)BN * 512 * 2);
    float4* ft4 = (float4*)alloc((size_t)32 * BN * 16);   // quad-packed knn features
    float* gbig = (float*)alloc((size_t)BN * 1024 * 4);  // Gz[0,BN*512) | hmax@BN*512 | g5 full
    int*   idx  = (int*)alloc((size_t)BN * KK * 4);
    unsigned int* ckey = (unsigned int*)alloc((size_t)BN * 2 * KK * 4);
    int*   cidx = (int*)alloc((size_t)BN * 2 * KK * 4);
    float* sqv  = (float*)alloc((size_t)BN * 4);
    float* s1g  = (float*)alloc(1024 * 4);
    float* s2g  = (float*)alloc(1024 * 4);
    float* spart  = (float*)alloc(2 * SLOTS * 256 * 4);     // conv1 fp32 stats
    float* spartC = (float*)alloc(2 * SLOTSM * 256 * 4);    // gmax stats
    float* spartW = (float*)alloc(2 * SLOTSW * 1024 * 4);   // w5 stats
    float* pmax = (float*)alloc(8 * 1024 * 8 * 4);
    float* psum = (float*)alloc(8 * 1024 * 8 * 4);
    float* pooled = (float*)alloc(8 * 2048 * 4);
    float* z1 = (float*)alloc(8 * 512 * 4);
    float* a1 = (float*)alloc(8 * 512 * 4);
    float* z2 = (float*)alloc(8 * 256 * 4);
    float* hfeat = (float*)alloc(8 * 768 * 4);
    float* Wa1 = (float*)alloc(4 * 64 * 4);
    float* Wd1 = (float*)alloc(4 * 64 * 4);
    unsigned short* WcH2 = (unsigned short*)alloc(128 * 64 * 2);
    unsigned short* WcL2 = (unsigned short*)alloc(128 * 64 * 2);
    unsigned short* WcH3 = (unsigned short*)alloc(256 * 64 * 2);
    unsigned short* WcL3 = (unsigned short*)alloc(256 * 64 * 2);
    unsigned short* WcH4 = (unsigned short*)alloc(512 * 128 * 2);
    unsigned short* WcL4 = (unsigned short*)alloc(512 * 128 * 2);
    unsigned short* w5H  = (unsigned short*)alloc(1024 * 512 * 2);
    unsigned short* w5L  = (unsigned short*)alloc(1024 * 512 * 2);
    float* s1p = spart;
    float* s2p = spart + SLOTS * 256;
    float* s1pc = spartC;
    float* s2pc = spartC + SLOTSM * 256;
    float* s1pw = spartW;
    float* s2pw = spartW + SLOTSW * 1024;
    float* hmaxP = gbig + (size_t)BN * 512;   // disjoint from Gz region [0, BN*512)

    // weight prep (plane-independent)
    k_prepw<<<(4 * 64 + 255) / 256, 256, 0, stream>>>(w1, 64, 3, 4, Wa1, Wd1);
    k_prepws2<<<(128 * 64 + 255) / 256, 256, 0, stream>>>(w2, 64, 64, WcH2, WcL2);
    k_prepws2<<<(256 * 64 + 255) / 256, 256, 0, stream>>>(w3, 128, 64, WcH3, WcL3);
    k_prepws2<<<(512 * 128 + 255) / 256, 256, 0, stream>>>(w4, 256, 128, WcH4, WcL4);
    k_splitw5<<<(1024 * 512) / 256, 256, 0, stream>>>(w5, w5H, w5L);

    const float inv_e = 1.f / (float)(BN * KK);
    for (int p = 0; p < 3; ++p) {
        k_transpose<<<BN / 256, 256, 0, stream>>>(x[p], xt);

        // ---- layer 1 (fp32): C=3 pad 4, O=64 -> cols 0:64 ; xt doubles as FT4 (CP4=1)
        k_sq4<1><<<BN / 256, 256, 0, stream>>>((const float4*)xt, sqv);
        k_knn3<4><<<NB * (NP / 8) * 2, 512, 0, stream>>>((const float4*)xt, sqv, ckey, cidx);
        k_kmerge<<<BN / 256, 256, 0, stream>>>(ckey, cidx, idx);
        hipMemsetAsync(spart, 0, 2 * SLOTS * 256 * 4, stream);
        k_conv<64, 4><<<BN / 2, 64, 0, stream>>>(xt, 4, idx, Wa1, Wd1, hmaxP, s1p, s2p);
        k_redslots<<<1, 256, 0, stream>>>(s1p, s2p, 64, SLOTS, s1g, s2g);
        k_bnmax<<<(BN * 64) / 256, 256, 0, stream>>>(hmaxP, 64, s1g, s2g, g1, b1, hcH, hcL, 512, 0, inv_e);
        k_pack4<<<dim3(BN / 64, 1), 256, 0, stream>>>(hcH, hcL, 0, ft4);

        // ---- layer 2: knn (CP=64 packed, m-split) + dense Gz (O2=128) + gather-max
        k_sq4<16><<<BN / 256, 256, 0, stream>>>(ft4, sqv);
        k_knn3<64><<<NB * (NP / 8) * 2, 512, 0, stream>>>(ft4, sqv, ckey, cidx);
        k_kmerge<<<BN / 256, 256, 0, stream>>>(ckey, cidx, idx);
        k_gemms<128, 64, 0><<<dim3(BN / 128, 2), 256, 0, stream>>>(hcH, hcL, WcH2, WcL2, gbig);
        hipMemsetAsync(spartC, 0, 2 * SLOTSM * 256 * 4, stream);
        k_gmax<64><<<BN / 4, 256, 0, stream>>>(gbig, idx, hmaxP, s1pc, s2pc);
        k_redslots<<<1, 256, 0, stream>>>(s1pc, s2pc, 64, SLOTSM, s1g, s2g);
        k_bnmax<<<(BN * 64) / 256, 256, 0, stream>>>(hmaxP, 64, s1g, s2g, g2, b2, hcH, hcL, 512, 64, inv_e);
        k_pack4<<<dim3(BN / 64, 1), 256, 0, stream>>>(hcH, hcL, 64, ft4);

        // ---- layer 3: O2=256
        k_sq4<16><<<BN / 256, 256, 0, stream>>>(ft4, sqv);
        k_knn3<64><<<NB * (NP / 8) * 2, 512, 0, stream>>>(ft4, sqv, ckey, cidx);
        k_kmerge<<<BN / 256, 256, 0, stream>>>(ckey, cidx, idx);
        k_gemms<256, 64, 64><<<dim3(BN / 128, 4), 256, 0, stream>>>(hcH, hcL, WcH3, WcL3, gbig);
        hipMemsetAsync(spartC, 0, 2 * SLOTSM * 256 * 4, stream);
        k_gmax<128><<<BN / 2, 256, 0, stream>>>(gbig, idx, hmaxP, s1pc, s2pc);
        k_redslots<<<1, 256, 0, stream>>>(s1pc, s2pc, 128, SLOTSM, s1g, s2g);
        k_bnmax<<<(BN * 128) / 256, 256, 0, stream>>>(hmaxP, 128, s1g, s2g, g3, b3, hcH, hcL, 512, 128, inv_e);
        k_pack4<<<dim3(BN / 64, 2), 256, 0, stream>>>(hcH, hcL, 128, ft4);

        // ---- layer 4: O2=512
        k_sq4<32><<<BN / 256, 256, 0, stream>>>(ft4, sqv);
        k_knn3<128><<<NB * (NP / 8) * 2, 512, 0, stream>>>(ft4, sqv, ckey, cidx);
        k_kmerge<<<BN / 256, 256, 0, stream>>>(ckey, cidx, idx);
        k_gemms<512, 128, 128><<<dim3(BN / 128, 8), 256, 0, stream>>>(hcH, hcL, WcH4, WcL4, gbig);
        hipMemsetAsync(spartC, 0, 2 * SLOTSM * 256 * 4, stream);
        k_gmax<256><<<BN, 256, 0, stream>>>(gbig, idx, hmaxP, s1pc, s2pc);
        k_redslots<<<1, 256, 0, stream>>>(s1pc, s2pc, 256, SLOTSM, s1g, s2g);
        k_bnmax<<<(BN * 256) / 256, 256, 0, stream>>>(hmaxP, 256, s1g, s2g, g4, b4, hcH, hcL, 512, 256, inv_e);

        // ---- w5 (mfma split, NT=4) + BN + pool
        hipMemsetAsync(spartW, 0, 2 * SLOTSW * 1024 * 4, stream);
        k_w5ms<<<dim3(BN / 32, 2), 256, 0, stream>>>(hcH, hcL, w5H, w5L, gbig, s1pw, s2pw);
        k_redslots<<<4, 256, 0, stream>>>(s1pw, s2pw, 1024, SLOTSW, s1g, s2g);
        k_pool<<<256, 256, 0, stream>>>(gbig, s1g, s2g, g5, b5, pmax, psum);
        k_poolfin<<<32, 256, 0, stream>>>(pmax, psum, pooled);

        // ---- FC head of the plane
        k_fc<2048><<<(8 * 512 + 255) / 256, 256, 0, stream>>>(pooled, wl1, nullptr, 512, z1);
        k_bnb<<<2, 256, 0, stream>>>(z1, 512, g6, b6, a1, 512, 0);
        k_fc<512><<<(8 * 256 + 255) / 256, 256, 0, stream>>>(a1, wl2, bl2, 256, z2);
        k_bnb<<<1, 256, 0, stream>>>(z2, 256, g7, b7, hfeat, 768, p * 256);
    }
    k_head<<<1, 64, 0, stream>>>(hfeat, whead, bhead, g8, b8, (float*)d_out);
}

// Round 20
// 2873.004 us; speedup vs baseline: 1.1672x; 1.1672x over previous
//
#include <hip/hip_runtime.h>
#include <hip/hip_bf16.h>
#include <cstdint>
#include <cstddef>

constexpr int NB = 8;      // batch
constexpr int NP = 2048;   // points per cloud
constexpr int BN = NB * NP;  // 16384
constexpr int KK = 20;     // neighbors
constexpr float EPSBN = 1e-5f;
constexpr float NEG = -3.402823466e38f;
constexpr int SLOTS = 8;    // fp32 conv1 stats slots
constexpr int SLOTSM = 32;  // gmax stats slots
constexpr int SLOTSW = 8;   // w5 stats slots

typedef __attribute__((ext_vector_type(8))) short bf16x8;   // 8 bf16 = 4 VGPRs
typedef __attribute__((ext_vector_type(16))) float f32x16;  // 32x32 MFMA acc

__device__ __forceinline__ float leaky(float x) { return x > 0.f ? x : 0.2f * x; }

__device__ __forceinline__ void split2(float x, unsigned short& h, unsigned short& l) {
    __hip_bfloat16 hh = __float2bfloat16(x);
    float hf = __bfloat162float(hh);
    __hip_bfloat16 ll = __float2bfloat16(x - hf);
    h = *reinterpret_cast<unsigned short*>(&hh);
    l = *reinterpret_cast<unsigned short*>(&ll);
}

__device__ __forceinline__ float b2f(unsigned short u) {
    __hip_bfloat16 h = *reinterpret_cast<__hip_bfloat16*>(&u);
    return __bfloat162float(h);
}

// float -> orderable u32 (ascending uint == ascending float)
__device__ __forceinline__ unsigned int f2key(float f) {
    unsigned int u = __float_as_uint(f);
    return u ^ (unsigned int)(((int)u >> 31) | 0x80000000);
}

// ---------------- transpose x [8,3,2048] -> xt [BN][4] (pad c3=0); xt doubles as FT4 (CP4=1)
__global__ void k_transpose(const float* __restrict__ x, float* __restrict__ xt) {
    int i = blockIdx.x * 256 + threadIdx.x;
    if (i >= BN) return;
    int b = i >> 11, n = i & 2047;
    float4 v;
    v.x = x[(b * 3 + 0) * NP + n];
    v.y = x[(b * 3 + 1) * NP + n];
    v.z = x[(b * 3 + 2) * NP + n];
    v.w = 0.f;
    *(float4*)&xt[(size_t)i * 4] = v;
}

// ---------------- sq from quad-packed FT4 [CP4][BN]
template <int CP4>
__global__ void k_sq4(const float4* __restrict__ FT4, float* __restrict__ sq) {
    int i = blockIdx.x * 256 + threadIdx.x;
    if (i >= BN) return;
    float s = 0.f;
#pragma unroll
    for (int cq = 0; cq < CP4; ++cq) {
        float4 f = FT4[(size_t)cq * BN + i];
        s += f.x * f.x + f.y * f.y + f.z * f.z + f.w * f.w;
    }
    sq[i] = s;
}

// ---------------- knn (all layers): R=8 rows/block, 512 threads, 64 KiB LDS keys,
// quad-packed FT4 loads. fp32 FMA order identical to prior rounds. Radix descend
// with exact early-exit (set-identical selection; wave-uniform branch).
template <int CP>
__launch_bounds__(512, 4)
__global__ void k_knn2(const float4* __restrict__ FT4, const float* __restrict__ sq,
                       int* __restrict__ gidx) {
    constexpr int R = 8;
    constexpr int CP4 = CP / 4;
    __shared__ unsigned int ds[R][NP];   // 64 KiB of keys
    int t = threadIdx.x;
    int b = blockIdx.x >> 8;            // NP/8 = 256 tiles per batch
    int n0 = (blockIdx.x & 255) * R;
    const float4* FTb = FT4 + (size_t)b * NP;
    const float* sqb = sq + (size_t)b * NP;

    float acc[R][4];
#pragma unroll
    for (int r = 0; r < R; ++r)
#pragma unroll
        for (int mi = 0; mi < 4; ++mi) acc[r][mi] = 0.f;

    for (int cq = 0; cq < CP4; ++cq) {
        float4 f[4];
#pragma unroll
        for (int mi = 0; mi < 4; ++mi)
            f[mi] = FTb[(size_t)cq * BN + t + mi * 512];
#pragma unroll
        for (int r = 0; r < R; ++r) {
            float4 cv = FTb[(size_t)cq * BN + n0 + r];
#pragma unroll
            for (int mi = 0; mi < 4; ++mi)
                acc[r][mi] += f[mi].x * cv.x + f[mi].y * cv.y + f[mi].z * cv.z + f[mi].w * cv.w;
        }
    }
#pragma unroll
    for (int mi = 0; mi < 4; ++mi) {
        int m = t + mi * 512;
        float sm = sqb[m];
#pragma unroll
        for (int r = 0; r < R; ++r) ds[r][m] = f2key(sm - 2.f * acc[r][mi]);
    }
    __syncthreads();

    // selection: 8 waves, wave handles row `wave`
    int wave = t >> 6, lane = t & 63;
    unsigned long long below = (1ull << lane) - 1ull;
    {
        int r = wave;
        unsigned int kv[32];
#pragma unroll
        for (int j = 0; j < 32; ++j) kv[j] = ds[r][lane + 64 * j];

        unsigned int T = 0;
        bool exact = false;
#pragma unroll 1
        for (int bit = 31; bit >= 0; --bit) {
            unsigned int tt = T | (1u << bit);
            int c = 0;
#pragma unroll
            for (int j = 0; j < 32; ++j)
                c += (int)__popcll(__ballot(kv[j] >= tt));
            if (c >= KK) {
                T = tt;
                if (c == KK) { exact = true; break; }
            }
        }

        int obase = (b * NP + n0 + r) * KK;
        if (exact) {
            // exactly KK elements satisfy kv >= T: the top-20 set, single pass
            int base = 0;
#pragma unroll 1
            for (int j = 0; j < 32; ++j) {
                bool pg = kv[j] >= T;
                unsigned long long mk = __ballot(pg);
                if (pg) gidx[obase + base + (int)__popcll(mk & below)] = lane + 64 * j;
                base += (int)__popcll(mk);
            }
        } else {
            int base = 0;
#pragma unroll 1
            for (int j = 0; j < 32; ++j) {
                bool pg = kv[j] > T;
                unsigned long long mk = __ballot(pg);
                if (pg) gidx[obase + base + (int)__popcll(mk & below)] = lane + 64 * j;
                base += (int)__popcll(mk);
            }
            int rem = KK - base;
#pragma unroll 1
            for (int j = 0; j < 32; ++j) {
                if (rem <= 0) break;
                bool pe = kv[j] == T;
                unsigned long long mk = __ballot(pe);
                int myp = (int)__popcll(mk & below);
                if (pe && myp < rem) gidx[obase + base + myp] = lane + 64 * j;
                int cnt = (int)__popcll(mk);
                int take = cnt < rem ? cnt : rem;
                base += take; rem -= take;
            }
        }
    }
}

// ---------------- prep (conv1, fp32): W [O][2C] -> WaT [CP][O], WdT [CP][O]
__global__ void k_prepw(const float* __restrict__ W, int O, int Cact, int CP,
                        float* __restrict__ WaT, float* __restrict__ WdT) {
    int i = blockIdx.x * 256 + threadIdx.x;
    if (i >= CP * O) return;
    int c = i / O, o = i % O;
    float wa = (c < Cact) ? W[o * 2 * Cact + c] : 0.f;
    float wb = (c < Cact) ? W[o * 2 * Cact + Cact + c] : 0.f;
    WaT[i] = wa;
    WdT[i] = wb - wa;
}

// ---------------- prep combined: W [O][2C] fp32 -> Wcmb [2O][C] split h/l
__global__ void k_prepws2(const float* __restrict__ W, int O, int C,
                          unsigned short* __restrict__ WcH, unsigned short* __restrict__ WcL) {
    int i = blockIdx.x * 256 + threadIdx.x;
    if (i >= 2 * O * C) return;
    int r = i / C, k = i % C;
    float v;
    if (r < O) v = W[r * 2 * C + k];
    else {
        int o = r - O;
        v = W[o * 2 * C + C + k] - W[o * 2 * C + k];
    }
    split2(v, WcH[i], WcL[i]);
}

// ---------------- split w5 [1024][512] fp32 -> hi/lo bf16
__global__ void k_splitw5(const float* __restrict__ w5, unsigned short* __restrict__ w5H,
                          unsigned short* __restrict__ w5L) {
    int i = blockIdx.x * 256 + threadIdx.x;
    if (i >= 1024 * 512) return;
    split2(w5[i], w5H[i], w5L[i]);
}

// ---------------- fp32 edge conv (layer 1 only, tiny C)
template <int O, int CP>
__launch_bounds__(O)
__global__ void k_conv(const float* __restrict__ F, int ld, const int* __restrict__ gidx,
                       const float* __restrict__ WaT, const float* __restrict__ WdT,
                       float* __restrict__ hmax, float* __restrict__ s1p,
                       float* __restrict__ s2p) {
    constexpr int CP4 = CP / 4;
    __shared__ float nbrT[2][CP][32];
    __shared__ float sctr[2][CP];
    __shared__ int sidx[2][KK];
    int t = threadIdx.x;
    int p0 = blockIdx.x * 2;
    int b = p0 >> 11;
    const float* Fb = F + (size_t)b * NP * ld;

    if (t < 2 * KK) {
        int pt = t / KK, k = t % KK;
        sidx[pt][k] = gidx[(size_t)(p0 + pt) * KK + k];
    }
    for (int e = t; e < 2 * CP; e += O) {
        int pt = e / CP, cc = e % CP;
        int n = (p0 + pt) & 2047;
        sctr[pt][cc] = Fb[(size_t)n * ld + cc];
    }
    __syncthreads();
    for (int e = t; e < 2 * KK * CP4; e += O) {
        int pt = e / (KK * CP4);
        int e2 = e % (KK * CP4);
        int k = e2 / CP4, cq = e2 % CP4;
        float4 f = *(const float4*)&Fb[(size_t)sidx[pt][k] * ld + cq * 4];
        int kp = (k + 4 * (cq & 7)) & 31;
        nbrT[pt][cq * 4 + 0][kp] = f.x;
        nbrT[pt][cq * 4 + 1][kp] = f.y;
        nbrT[pt][cq * 4 + 2][kp] = f.z;
        nbrT[pt][cq * 4 + 3][kp] = f.w;
    }
    __syncthreads();

    int o = t;
    float bacc0 = 0.f, bacc1 = 0.f;
#pragma unroll 4
    for (int c = 0; c < CP; ++c) {
        float w = WdT[c * O + o];
        bacc0 += sctr[0][c] * w;
        bacc1 += sctr[1][c] * w;
    }
    float a0[KK], a1[KK];
#pragma unroll
    for (int k = 0; k < KK; ++k) { a0[k] = 0.f; a1[k] = 0.f; }
#pragma unroll 2
    for (int c = 0; c < CP; ++c) {
        float w = WaT[c * O + o];
        int s = 4 * ((c >> 2) & 7);
#pragma unroll
        for (int kq = 0; kq < KK / 4; ++kq) {
            int kp = (4 * kq + s) & 31;
            float4 f0 = *(const float4*)&nbrT[0][c][kp];
            float4 f1 = *(const float4*)&nbrT[1][c][kp];
            a0[kq * 4 + 0] += w * f0.x; a1[kq * 4 + 0] += w * f1.x;
            a0[kq * 4 + 1] += w * f0.y; a1[kq * 4 + 1] += w * f1.y;
            a0[kq * 4 + 2] += w * f0.z; a1[kq * 4 + 2] += w * f1.z;
            a0[kq * 4 + 3] += w * f0.w; a1[kq * 4 + 3] += w * f1.w;
        }
    }
    float hm0 = NEG, hm1 = NEG, ts1 = 0.f, ts2 = 0.f;
#pragma unroll
    for (int k = 0; k < KK; ++k) {
        float h0 = a0[k] + bacc0;
        float h1 = a1[k] + bacc1;
        hm0 = fmaxf(hm0, h0); hm1 = fmaxf(hm1, h1);
        ts1 += h0 + h1; ts2 += h0 * h0 + h1 * h1;
    }
    hmax[(size_t)p0 * O + o] = hm0;
    hmax[(size_t)(p0 + 1) * O + o] = hm1;
    int slot = blockIdx.x & (SLOTS - 1);
    atomicAdd(&s1p[slot * O + o], ts1);
    atomicAdd(&s2p[slot * O + o], ts2);
}

// ---------------- dense split GEMM: Gz[BN][O] = hc[:, COFF:COFF+C] @ Wcmb^T (fp32 out)
template <int O, int C, int COFF>
__launch_bounds__(256, 4)
__global__ void k_gemms(const unsigned short* __restrict__ hcH,
                        const unsigned short* __restrict__ hcL,
                        const unsigned short* __restrict__ WdH,
                        const unsigned short* __restrict__ WdL,
                        float* __restrict__ bacc) {
    constexpr int KS = C / 16;
    int tid = threadIdx.x, wave = tid >> 6, lane = tid & 63;
    int row = lane & 31, half = lane >> 5;
    int p0 = blockIdx.x * 128 + wave * 32;
    int ob = blockIdx.y * 64;
    const unsigned short* aH = hcH + (size_t)(p0 + row) * 512 + COFF;
    const unsigned short* aL = hcL + (size_t)(p0 + row) * 512 + COFF;
    f32x16 acc[2];
#pragma unroll
    for (int nt = 0; nt < 2; ++nt)
#pragma unroll
        for (int r = 0; r < 16; ++r) acc[nt][r] = 0.f;

#pragma unroll 2
    for (int ks = 0; ks < KS; ++ks) {
        int k0 = ks * 16 + half * 8;
        bf16x8 avh = *(const bf16x8*)(aH + k0);
        bf16x8 avl = *(const bf16x8*)(aL + k0);
#pragma unroll
        for (int nt = 0; nt < 2; ++nt) {
            int j = ob + nt * 32 + row;
            bf16x8 bvh = *(const bf16x8*)(WdH + (size_t)j * C + k0);
            bf16x8 bvl = *(const bf16x8*)(WdL + (size_t)j * C + k0);
            acc[nt] = __builtin_amdgcn_mfma_f32_32x32x16_bf16(avh, bvh, acc[nt], 0, 0, 0);
            acc[nt] = __builtin_amdgcn_mfma_f32_32x32x16_bf16(avh, bvl, acc[nt], 0, 0, 0);
            acc[nt] = __builtin_amdgcn_mfma_f32_32x32x16_bf16(avl, bvh, acc[nt], 0, 0, 0);
        }
    }
#pragma unroll
    for (int nt = 0; nt < 2; ++nt)
#pragma unroll
        for (int r = 0; r < 16; ++r) {
            int i = (r & 3) + 8 * (r >> 2) + 4 * half;
            bacc[(size_t)(p0 + i) * O + ob + nt * 32 + row] = acc[nt][r];
        }
}

// ---------------- gather-max epilogue: hmax[p,o] = max_k Gz[nbr_k, o] + bacc
template <int O>
__launch_bounds__(256)
__global__ void k_gmax(const float* __restrict__ Gz, const int* __restrict__ gidx,
                       float* __restrict__ hmax, float* __restrict__ s1p,
                       float* __restrict__ s2p) {
    constexpr int PB = 256 / O;      // points per block
    constexpr int O2 = 2 * O;
    __shared__ int sidx[PB][KK];
    int t = threadIdx.x;
    int pt = t / O, o = t % O;
    int p0 = blockIdx.x * PB;
    if (t < PB * KK) sidx[t / KK][t % KK] = gidx[(size_t)(p0 + t / KK) * KK + t % KK];
    __syncthreads();

    int p = p0 + pt;
    int b = p >> 11;
    const float* Gb = Gz + (size_t)b * 2048 * O2;
    float bacc = Gz[(size_t)p * O2 + O + o];
    float mx = NEG, ts1 = 0.f, ts2 = 0.f;
#pragma unroll 5
    for (int k = 0; k < KK; ++k) {
        float g = Gb[(size_t)sidx[pt][k] * O2 + o];
        float h = g + bacc;
        mx = fmaxf(mx, g);
        ts1 += h; ts2 += h * h;
    }
    hmax[(size_t)p * O + o] = mx + bacc;
    int slot = blockIdx.x & (SLOTSM - 1);
    atomicAdd(&s1p[slot * O + o], ts1);
    atomicAdd(&s2p[slot * O + o], ts2);
}

// ---------------- reduce slotted stats -> s1g/s2g
__global__ void k_redslots(const float* __restrict__ s1p, const float* __restrict__ s2p,
                           int O, int S, float* __restrict__ s1g, float* __restrict__ s2g) {
    int o = blockIdx.x * 256 + threadIdx.x;
    if (o >= O) return;
    float a = 0.f, c = 0.f;
    for (int s = 0; s < S; ++s) { a += s1p[s * O + o]; c += s2p[s * O + o]; }
    s1g[o] = a; s2g[o] = c;
}

// ---------------- BN(+leaky) on per-point max; writes split hi/lo bf16
__global__ void k_bnmax(const float* __restrict__ hmax, int O, const float* __restrict__ s1g,
                        const float* __restrict__ s2g, const float* __restrict__ gam,
                        const float* __restrict__ bet, unsigned short* __restrict__ outH,
                        unsigned short* __restrict__ outL, int ostride, int ooff,
                        float inv_cnt) {
    int i = blockIdx.x * 256 + threadIdx.x;
    if (i >= BN * O) return;
    int o = i % O, p = i / O;
    float m = s1g[o] * inv_cnt;
    float v = s2g[o] * inv_cnt - m * m;
    float rs = rsqrtf(v + EPSBN);
    float y = leaky(gam[o] * (hmax[i] - m) * rs + bet[o]);
    size_t oi = (size_t)p * ostride + ooff + o;
    split2(y, outH[oi], outL[oi]);
}

// ---------------- pack: hi/lo bf16 cols [coff+o0,...) -> quad-packed FT4 [CP4][BN]
__global__ void k_pack4(const unsigned short* __restrict__ inH,
                        const unsigned short* __restrict__ inL, int coff,
                        float4* __restrict__ out) {
    __shared__ float tile[64][65];
    int tx = threadIdx.x & 63, ty = threadIdx.x >> 6;
    int p0 = blockIdx.x * 64, o0 = blockIdx.y * 64;
    for (int i = ty; i < 64; i += 4) {
        size_t idx = (size_t)(p0 + i) * 512 + coff + o0 + tx;
        tile[i][tx] = b2f(inH[idx]) + b2f(inL[idx]);
    }
    __syncthreads();
    for (int q = ty; q < 16; q += 4) {
        float4 v;
        v.x = tile[tx][4 * q + 0];
        v.y = tile[tx][4 * q + 1];
        v.z = tile[tx][4 * q + 2];
        v.w = tile[tx][4 * q + 3];
        out[(size_t)(o0 / 4 + q) * BN + p0 + tx] = v;
    }
}

// ---------------- w5 split GEMM: g5 = hc[BN][512] @ w5^T -> fp32 [BN][1024] + stats
// NT=4 (wave covers 128 cols), grid.y = 2.
__launch_bounds__(256, 3)
__global__ void k_w5ms(const unsigned short* __restrict__ hcH,
                       const unsigned short* __restrict__ hcL,
                       const unsigned short* __restrict__ w5H,
                       const unsigned short* __restrict__ w5L,
                       float* __restrict__ g5, float* __restrict__ s1p,
                       float* __restrict__ s2p) {
    int tid = threadIdx.x, wave = tid >> 6, lane = tid & 63;
    int row = lane & 31, half = lane >> 5;
    int p0 = blockIdx.x * 32;
    int ob = blockIdx.y * 512 + wave * 128;
    const unsigned short* aH = hcH + (size_t)(p0 + row) * 512;
    const unsigned short* aL = hcL + (size_t)(p0 + row) * 512;
    f32x16 acc[4];
#pragma unroll
    for (int nt = 0; nt < 4; ++nt)
#pragma unroll
        for (int r = 0; r < 16; ++r) acc[nt][r] = 0.f;

#pragma unroll 2
    for (int ks = 0; ks < 32; ++ks) {
        int k0 = ks * 16 + half * 8;
        bf16x8 avh = *(const bf16x8*)(aH + k0);
        bf16x8 avl = *(const bf16x8*)(aL + k0);
#pragma unroll
        for (int nt = 0; nt < 4; ++nt) {
            int j = ob + nt * 32 + row;
            bf16x8 bvh = *(const bf16x8*)(w5H + (size_t)j * 512 + k0);
            bf16x8 bvl = *(const bf16x8*)(w5L + (size_t)j * 512 + k0);
            acc[nt] = __builtin_amdgcn_mfma_f32_32x32x16_bf16(avh, bvh, acc[nt], 0, 0, 0);
            acc[nt] = __builtin_amdgcn_mfma_f32_32x32x16_bf16(avh, bvl, acc[nt], 0, 0, 0);
            acc[nt] = __builtin_amdgcn_mfma_f32_32x32x16_bf16(avl, bvh, acc[nt], 0, 0, 0);
        }
    }
    int slot = blockIdx.x & (SLOTSW - 1);
#pragma unroll
    for (int nt = 0; nt < 4; ++nt) {
        int j = ob + nt * 32 + row;
        float s1 = 0.f, s2 = 0.f;
#pragma unroll
        for (int r = 0; r < 16; ++r) {
            int i = (r & 3) + 8 * (r >> 2) + 4 * half;
            float v = acc[nt][r];
            g5[(size_t)(p0 + i) * 1024 + j] = v;
            s1 += v; s2 += v * v;
        }
        s1 += __shfl_xor(s1, 32);
        s2 += __shfl_xor(s2, 32);
        if (half == 0) {
            atomicAdd(&s1p[slot * 1024 + j], s1);
            atomicAdd(&s2p[slot * 1024 + j], s2);
        }
    }
}

// ---------------- pool: per (b, o-tile, n-chunk) partial max / partial sum
__global__ void k_pool(const float* __restrict__ gbuf, const float* __restrict__ s1g,
                       const float* __restrict__ s2g, const float* __restrict__ gam,
                       const float* __restrict__ bet, float* __restrict__ pmax,
                       float* __restrict__ psum) {
    int t = threadIdx.x;
    int blk = blockIdx.x;
    int nc = blk & 7, ot = (blk >> 3) & 3, b = blk >> 5;
    int o = ot * 256 + t;
    float m = s1g[o] * (1.f / 16384.f);
    float v = s2g[o] * (1.f / 16384.f) - m * m;
    float rs = rsqrtf(v + EPSBN);
    float ga = gam[o], be = bet[o];
    float vmax = NEG, vsum = 0.f;
    for (int j = 0; j < 256; ++j) {
        int n = nc * 256 + j;
        float x = gbuf[((size_t)b * NP + n) * 1024 + o];
        float y = leaky(ga * (x - m) * rs + be);
        vmax = fmaxf(vmax, y);
        vsum += y;
    }
    pmax[(b * 1024 + o) * 8 + nc] = vmax;
    psum[(b * 1024 + o) * 8 + nc] = vsum;
}

__global__ void k_poolfin(const float* __restrict__ pmax, const float* __restrict__ psum,
                          float* __restrict__ pooled) {
    int i = blockIdx.x * 256 + threadIdx.x;
    if (i >= 8192) return;
    float mx = NEG, sm = 0.f;
    for (int j = 0; j < 8; ++j) {
        mx = fmaxf(mx, pmax[i * 8 + j]);
        sm += psum[i * 8 + j];
    }
    int b = i >> 10, o = i & 1023;
    pooled[b * 2048 + o] = mx;
    pooled[b * 2048 + 1024 + o] = sm * (1.f / 2048.f);
}

// ---------------- small FC: z[b][o] = in[b] . W[o] (+bias)
template <int CIN>
__global__ void k_fc(const float* __restrict__ in, const float* __restrict__ W,
                     const float* __restrict__ bias, int O, float* __restrict__ z) {
    int i = blockIdx.x * 256 + threadIdx.x;
    if (i >= NB * O) return;
    int b = i / O, o = i % O;
    const float* wr = W + (size_t)o * CIN;
    const float* ir = in + (size_t)b * CIN;
    float acc = 0.f;
#pragma unroll 4
    for (int cq = 0; cq < CIN / 4; ++cq) {
        float4 wv = *(const float4*)&wr[cq * 4];
        float4 iv = *(const float4*)&ir[cq * 4];
        acc += wv.x * iv.x + wv.y * iv.y + wv.z * iv.z + wv.w * iv.w;
    }
    z[i] = acc + (bias ? bias[o] : 0.f);
}

// ---------------- BN over batch (8 samples) + leaky
__global__ void k_bnb(const float* __restrict__ z, int O, const float* __restrict__ gam,
                      const float* __restrict__ bet, float* __restrict__ out, int ostride,
                      int ooff) {
    int o = blockIdx.x * 256 + threadIdx.x;
    if (o >= O) return;
    float s1 = 0.f, s2 = 0.f;
#pragma unroll
    for (int b = 0; b < NB; ++b) {
        float x = z[b * O + o];
        s1 += x; s2 += x * x;
    }
    float m = s1 * 0.125f, v = s2 * 0.125f - m * m;
    float rs = rsqrtf(v + EPSBN);
    float ga = gam[o], be = bet[o];
    for (int b = 0; b < NB; ++b) {
        float y = ga * (z[b * O + o] - m) * rs + be;
        out[b * ostride + ooff + o] = leaky(y);
    }
}

// ---------------- head
__global__ void k_head(const float* __restrict__ hf, const float* __restrict__ wh,
                       const float* __restrict__ bh, const float* __restrict__ g8,
                       const float* __restrict__ b8, float* __restrict__ out) {
    __shared__ float zh[56];
    int t = threadIdx.x;
    if (t < 56) {
        int b = t / 7, o = t % 7;
        float acc = bh[o];
        for (int c = 0; c < 768; ++c) acc += hf[b * 768 + c] * wh[o * 768 + c];
        zh[t] = acc;
    }
    __syncthreads();
    if (t < 7) {
        float s1 = 0.f, s2 = 0.f;
        for (int b = 0; b < NB; ++b) {
            float x = zh[b * 7 + t];
            s1 += x; s2 += x * x;
        }
        float m = s1 * 0.125f, v = s2 * 0.125f - m * m;
        float rs = rsqrtf(v + EPSBN);
        for (int b = 0; b < NB; ++b) {
            float y = g8[t] * (zh[b * 7 + t] - m) * rs + b8[t];
            out[b * 7 + t] = fmaxf(y, 0.f);
        }
    }
}

extern "C" void kernel_launch(void* const* d_in, const int* in_sizes, int n_in, void* d_out,
                              int out_size, void* d_ws, size_t ws_size, hipStream_t stream) {
    const float* x[3] = {(const float*)d_in[0], (const float*)d_in[1], (const float*)d_in[2]};
    const float* w1 = (const float*)d_in[3];
    const float* w2 = (const float*)d_in[4];
    const float* w3 = (const float*)d_in[5];
    const float* w4 = (const float*)d_in[6];
    const float* w5 = (const float*)d_in[7];
    const float* wl1 = (const float*)d_in[8];
    const float* wl2 = (const float*)d_in[9];
    const float* bl2 = (const float*)d_in[10];
    const float* whead = (const float*)d_in[11];
    const float* bhead = (const float*)d_in[12];
    const float *g1 = (const float*)d_in[13], *b1 = (const float*)d_in[14];
    const float *g2 = (const float*)d_in[15], *b2 = (const float*)d_in[16];
    const float *g3 = (const float*)d_in[17], *b3 = (const float*)d_in[18];
    const float *g4 = (const float*)d_in[19], *b4 = (const float*)d_in[20];
    const float *g5 = (const float*)d_in[21], *b5 = (const float*)d_in[22];
    const float *g6 = (const float*)d_in[23], *b6 = (const float*)d_in[24];
    const float *g7 = (const float*)d_in[25], *b7 = (const float*)d_in[26];
    const float *g8 = (const float*)d_in[27], *b8 = (const float*)d_in[28];

    char* w = (char*)d_ws;
    auto alloc = [&](size_t bytes) {
        char* p = w;
        w += (bytes + 255) & ~(size_t)255;
        return p;
    };
    float* xt   = (float*)alloc((size_t)BN * 4 * 4);
    unsigned short* hcH = (unsigned short*)alloc((size_t)BN * 512 * 2);
    unsigned short* hcL = (unsigned short*)alloc((size_t)BN * 512 * 2);
    float4* ft4 = (float4*)alloc((size_t)32 * BN * 16);   // quad-packed knn features
    float* gbig = (float*)alloc((size_t)BN * 1024 * 4);  // Gz[0,BN*512) | hmax@BN*512 | g5 full
    int*   idx  = (int*)alloc((size_t)BN * KK * 4);
    float* sqv  = (float*)alloc((size_t)BN * 4);
    float* s1g  = (float*)alloc(1024 * 4);
    float* s2g  = (float*)alloc(1024 * 4);
    float* spart  = (float*)alloc(2 * SLOTS * 256 * 4);     // conv1 fp32 stats
    float* spartC = (float*)alloc(2 * SLOTSM * 256 * 4);    // gmax stats
    float* spartW = (float*)alloc(2 * SLOTSW * 1024 * 4);   // w5 stats
    float* pmax = (float*)alloc(8 * 1024 * 8 * 4);
    float* psum = (float*)alloc(8 * 1024 * 8 * 4);
    float* pooled = (float*)alloc(8 * 2048 * 4);
    float* z1 = (float*)alloc(8 * 512 * 4);
    float* a1 = (float*)alloc(8 * 512 * 4);
    float* z2 = (float*)alloc(8 * 256 * 4);
    float* hfeat = (float*)alloc(8 * 768 * 4);
    float* Wa1 = (float*)alloc(4 * 64 * 4);
    float* Wd1 = (float*)alloc(4 * 64 * 4);
    unsigned short* WcH2 = (unsigned short*)alloc(128 * 64 * 2);
    unsigned short* WcL2 = (unsigned short*)alloc(128 * 64 * 2);
    unsigned short* WcH3 = (unsigned short*)alloc(256 * 64 * 2);
    unsigned short* WcL3 = (unsigned short*)alloc(256 * 64 * 2);
    unsigned short* WcH4 = (unsigned short*)alloc(512 * 128 * 2);
    unsigned short* WcL4 = (unsigned short*)alloc(512 * 128 * 2);
    unsigned short* w5H  = (unsigned short*)alloc(1024 * 512 * 2);
    unsigned short* w5L  = (unsigned short*)alloc(1024 * 512 * 2);
    float* s1p = spart;
    float* s2p = spart + SLOTS * 256;
    float* s1pc = spartC;
    float* s2pc = spartC + SLOTSM * 256;
    float* s1pw = spartW;
    float* s2pw = spartW + SLOTSW * 1024;
    float* hmaxP = gbig + (size_t)BN * 512;   // disjoint from Gz region [0, BN*512)

    // weight prep (plane-independent)
    k_prepw<<<(4 * 64 + 255) / 256, 256, 0, stream>>>(w1, 64, 3, 4, Wa1, Wd1);
    k_prepws2<<<(128 * 64 + 255) / 256, 256, 0, stream>>>(w2, 64, 64, WcH2, WcL2);
    k_prepws2<<<(256 * 64 + 255) / 256, 256, 0, stream>>>(w3, 128, 64, WcH3, WcL3);
    k_prepws2<<<(512 * 128 + 255) / 256, 256, 0, stream>>>(w4, 256, 128, WcH4, WcL4);
    k_splitw5<<<(1024 * 512) / 256, 256, 0, stream>>>(w5, w5H, w5L);

    const float inv_e = 1.f / (float)(BN * KK);
    for (int p = 0; p < 3; ++p) {
        k_transpose<<<BN / 256, 256, 0, stream>>>(x[p], xt);

        // ---- layer 1 (fp32): C=3 pad 4, O=64 -> cols 0:64 ; xt doubles as FT4 (CP4=1)
        k_sq4<1><<<BN / 256, 256, 0, stream>>>((const float4*)xt, sqv);
        k_knn2<4><<<NB * (NP / 8), 512, 0, stream>>>((const float4*)xt, sqv, idx);
        hipMemsetAsync(spart, 0, 2 * SLOTS * 256 * 4, stream);
        k_conv<64, 4><<<BN / 2, 64, 0, stream>>>(xt, 4, idx, Wa1, Wd1, hmaxP, s1p, s2p);
        k_redslots<<<1, 256, 0, stream>>>(s1p, s2p, 64, SLOTS, s1g, s2g);
        k_bnmax<<<(BN * 64) / 256, 256, 0, stream>>>(hmaxP, 64, s1g, s2g, g1, b1, hcH, hcL, 512, 0, inv_e);
        k_pack4<<<dim3(BN / 64, 1), 256, 0, stream>>>(hcH, hcL, 0, ft4);

        // ---- layer 2: knn (CP=64 packed) + dense Gz=[G|bacc] (O2=128) + gather-max
        k_sq4<16><<<BN / 256, 256, 0, stream>>>(ft4, sqv);
        k_knn2<64><<<NB * (NP / 8), 512, 0, stream>>>(ft4, sqv, idx);
        k_gemms<128, 64, 0><<<dim3(BN / 128, 2), 256, 0, stream>>>(hcH, hcL, WcH2, WcL2, gbig);
        hipMemsetAsync(spartC, 0, 2 * SLOTSM * 256 * 4, stream);
        k_gmax<64><<<BN / 4, 256, 0, stream>>>(gbig, idx, hmaxP, s1pc, s2pc);
        k_redslots<<<1, 256, 0, stream>>>(s1pc, s2pc, 64, SLOTSM, s1g, s2g);
        k_bnmax<<<(BN * 64) / 256, 256, 0, stream>>>(hmaxP, 64, s1g, s2g, g2, b2, hcH, hcL, 512, 64, inv_e);
        k_pack4<<<dim3(BN / 64, 1), 256, 0, stream>>>(hcH, hcL, 64, ft4);

        // ---- layer 3: O2=256
        k_sq4<16><<<BN / 256, 256, 0, stream>>>(ft4, sqv);
        k_knn2<64><<<NB * (NP / 8), 512, 0, stream>>>(ft4, sqv, idx);
        k_gemms<256, 64, 64><<<dim3(BN / 128, 4), 256, 0, stream>>>(hcH, hcL, WcH3, WcL3, gbig);
        hipMemsetAsync(spartC, 0, 2 * SLOTSM * 256 * 4, stream);
        k_gmax<128><<<BN / 2, 256, 0, stream>>>(gbig, idx, hmaxP, s1pc, s2pc);
        k_redslots<<<1, 256, 0, stream>>>(s1pc, s2pc, 128, SLOTSM, s1g, s2g);
        k_bnmax<<<(BN * 128) / 256, 256, 0, stream>>>(hmaxP, 128, s1g, s2g, g3, b3, hcH, hcL, 512, 128, inv_e);
        k_pack4<<<dim3(BN / 64, 2), 256, 0, stream>>>(hcH, hcL, 128, ft4);

        // ---- layer 4: O2=512
        k_sq4<32><<<BN / 256, 256, 0, stream>>>(ft4, sqv);
        k_knn2<128><<<NB * (NP / 8), 512, 0, stream>>>(ft4, sqv, idx);
        k_gemms<512, 128, 128><<<dim3(BN / 128, 8), 256, 0, stream>>>(hcH, hcL, WcH4, WcL4, gbig);
        hipMemsetAsync(spartC, 0, 2 * SLOTSM * 256 * 4, stream);
        k_gmax<256><<<BN, 256, 0, stream>>>(gbig, idx, hmaxP, s1pc, s2pc);
        k_redslots<<<1, 256, 0, stream>>>(s1pc, s2pc, 256, SLOTSM, s1g, s2g);
        k_bnmax<<<(BN * 256) / 256, 256, 0, stream>>>(hmaxP, 256, s1g, s2g, g4, b4, hcH, hcL, 512, 256, inv_e);

        // ---- w5 (mfma split, NT=4) + BN + pool
        hipMemsetAsync(spartW, 0, 2 * SLOTSW * 1024 * 4, stream);
        k_w5ms<<<dim3(BN / 32, 2), 256, 0, stream>>>(hcH, hcL, w5H, w5L, gbig, s1pw, s2pw);
        k_redslots<<<4, 256, 0, stream>>>(s1pw, s2pw, 1024, SLOTSW, s1g, s2g);
        k_pool<<<256, 256, 0, stream>>>(gbig, s1g, s2g, g5, b5, pmax, psum);
        k_poolfin<<<32, 256, 0, stream>>>(pmax, psum, pooled);

        // ---- FC head of the plane
        k_fc<2048><<<(8 * 512 + 255) / 256, 256, 0, stream>>>(pooled, wl1, nullptr, 512, z1);
        k_bnb<<<2, 256, 0, stream>>>(z1, 512, g6, b6, a1, 512, 0);
        k_fc<512><<<(8 * 256 + 255) / 256, 256, 0, stream>>>(a1, wl2, bl2, 256, z2);
        k_bnb<<<1, 256, 0, stream>>>(z2, 256, g7, b7, hfeat, 768, p * 256);
    }
    k_head<<<1, 64, 0, stream>>>(hfeat, whead, bhead, g8, b8, (float*)d_out);
}

// Round 21
// 2671.703 us; speedup vs baseline: 1.2552x; 1.0753x over previous
//
#include <hip/hip_runtime.h>
#include <hip/hip_bf16.h>
#include <cstdint>
#include <cstddef>

constexpr int NB = 8;      // batch
constexpr int NP = 2048;   // points per cloud
constexpr int BN = NB * NP;  // 16384
constexpr int KK = 20;     // neighbors
constexpr float EPSBN = 1e-5f;
constexpr float NEG = -3.402823466e38f;
constexpr int SLOTS = 8;    // fp32 conv1 stats slots
constexpr int SLOTSM = 32;  // gmax stats slots
constexpr int SLOTSW = 8;   // w5 stats slots

typedef __attribute__((ext_vector_type(8))) short bf16x8;   // 8 bf16 = 4 VGPRs
typedef __attribute__((ext_vector_type(16))) float f32x16;  // 32x32 MFMA acc

__device__ __forceinline__ float leaky(float x) { return x > 0.f ? x : 0.2f * x; }

__device__ __forceinline__ void split2(float x, unsigned short& h, unsigned short& l) {
    __hip_bfloat16 hh = __float2bfloat16(x);
    float hf = __bfloat162float(hh);
    __hip_bfloat16 ll = __float2bfloat16(x - hf);
    h = *reinterpret_cast<unsigned short*>(&hh);
    l = *reinterpret_cast<unsigned short*>(&ll);
}

__device__ __forceinline__ float b2f(unsigned short u) {
    __hip_bfloat16 h = *reinterpret_cast<__hip_bfloat16*>(&u);
    return __bfloat162float(h);
}

// float -> orderable u32 (ascending uint == ascending float)
__device__ __forceinline__ unsigned int f2key(float f) {
    unsigned int u = __float_as_uint(f);
    return u ^ (unsigned int)(((int)u >> 31) | 0x80000000);
}

// ---------------- transpose x [8,3,2048] -> xt [BN][4] (pad c3=0); xt doubles as FT4 (CP4=1)
__global__ void k_transpose(const float* __restrict__ x, float* __restrict__ xt) {
    int i = blockIdx.x * 256 + threadIdx.x;
    if (i >= BN) return;
    int b = i >> 11, n = i & 2047;
    float4 v;
    v.x = x[(b * 3 + 0) * NP + n];
    v.y = x[(b * 3 + 1) * NP + n];
    v.z = x[(b * 3 + 2) * NP + n];
    v.w = 0.f;
    *(float4*)&xt[(size_t)i * 4] = v;
}

// ---------------- sq from quad-packed FT4 [CP4][BN]
template <int CP4>
__global__ void k_sq4(const float4* __restrict__ FT4, float* __restrict__ sq) {
    int i = blockIdx.x * 256 + threadIdx.x;
    if (i >= BN) return;
    float s = 0.f;
#pragma unroll
    for (int cq = 0; cq < CP4; ++cq) {
        float4 f = FT4[(size_t)cq * BN + i];
        s += f.x * f.x + f.y * f.y + f.z * f.z + f.w * f.w;
    }
    sq[i] = s;
}

// ---------------- knn (all layers): R=8 rows/block, 512 threads, 64 KiB LDS keys,
// quad-packed FT4 loads. fp32 FMA order identical to prior rounds. Radix descend
// with exact early-exit (set-identical selection; wave-uniform branch).
template <int CP>
__launch_bounds__(512, 4)
__global__ void k_knn2(const float4* __restrict__ FT4, const float* __restrict__ sq,
                       int* __restrict__ gidx) {
    constexpr int R = 8;
    constexpr int CP4 = CP / 4;
    __shared__ unsigned int ds[R][NP];   // 64 KiB of keys
    int t = threadIdx.x;
    int b = blockIdx.x >> 8;            // NP/8 = 256 tiles per batch
    int n0 = (blockIdx.x & 255) * R;
    const float4* FTb = FT4 + (size_t)b * NP;
    const float* sqb = sq + (size_t)b * NP;

    float acc[R][4];
#pragma unroll
    for (int r = 0; r < R; ++r)
#pragma unroll
        for (int mi = 0; mi < 4; ++mi) acc[r][mi] = 0.f;

    for (int cq = 0; cq < CP4; ++cq) {
        float4 f[4];
#pragma unroll
        for (int mi = 0; mi < 4; ++mi)
            f[mi] = FTb[(size_t)cq * BN + t + mi * 512];
#pragma unroll
        for (int r = 0; r < R; ++r) {
            float4 cv = FTb[(size_t)cq * BN + n0 + r];
#pragma unroll
            for (int mi = 0; mi < 4; ++mi)
                acc[r][mi] += f[mi].x * cv.x + f[mi].y * cv.y + f[mi].z * cv.z + f[mi].w * cv.w;
        }
    }
#pragma unroll
    for (int mi = 0; mi < 4; ++mi) {
        int m = t + mi * 512;
        float sm = sqb[m];
#pragma unroll
        for (int r = 0; r < R; ++r) ds[r][m] = f2key(sm - 2.f * acc[r][mi]);
    }
    __syncthreads();

    // selection: 8 waves, wave handles row `wave`
    int wave = t >> 6, lane = t & 63;
    unsigned long long below = (1ull << lane) - 1ull;
    {
        int r = wave;
        unsigned int kv[32];
#pragma unroll
        for (int j = 0; j < 32; ++j) kv[j] = ds[r][lane + 64 * j];

        unsigned int T = 0;
        bool exact = false;
#pragma unroll 1
        for (int bit = 31; bit >= 0; --bit) {
            unsigned int tt = T | (1u << bit);
            int c = 0;
#pragma unroll
            for (int j = 0; j < 32; ++j)
                c += (int)__popcll(__ballot(kv[j] >= tt));
            if (c >= KK) {
                T = tt;
                if (c == KK) { exact = true; break; }
            }
        }

        int obase = (b * NP + n0 + r) * KK;
        if (exact) {
            // exactly KK elements satisfy kv >= T: the top-20 set, single pass
            int base = 0;
#pragma unroll 1
            for (int j = 0; j < 32; ++j) {
                bool pg = kv[j] >= T;
                unsigned long long mk = __ballot(pg);
                if (pg) gidx[obase + base + (int)__popcll(mk & below)] = lane + 64 * j;
                base += (int)__popcll(mk);
            }
        } else {
            int base = 0;
#pragma unroll 1
            for (int j = 0; j < 32; ++j) {
                bool pg = kv[j] > T;
                unsigned long long mk = __ballot(pg);
                if (pg) gidx[obase + base + (int)__popcll(mk & below)] = lane + 64 * j;
                base += (int)__popcll(mk);
            }
            int rem = KK - base;
#pragma unroll 1
            for (int j = 0; j < 32; ++j) {
                if (rem <= 0) break;
                bool pe = kv[j] == T;
                unsigned long long mk = __ballot(pe);
                int myp = (int)__popcll(mk & below);
                if (pe && myp < rem) gidx[obase + base + myp] = lane + 64 * j;
                int cnt = (int)__popcll(mk);
                int take = cnt < rem ? cnt : rem;
                base += take; rem -= take;
            }
        }
    }
}

// ---------------- prep (conv1, fp32): W [O][2C] -> WaT [CP][O], WdT [CP][O]
__global__ void k_prepw(const float* __restrict__ W, int O, int Cact, int CP,
                        float* __restrict__ WaT, float* __restrict__ WdT) {
    int i = blockIdx.x * 256 + threadIdx.x;
    if (i >= CP * O) return;
    int c = i / O, o = i % O;
    float wa = (c < Cact) ? W[o * 2 * Cact + c] : 0.f;
    float wb = (c < Cact) ? W[o * 2 * Cact + Cact + c] : 0.f;
    WaT[i] = wa;
    WdT[i] = wb - wa;
}

// ---------------- prep combined: W [O][2C] fp32 -> Wcmb [2O][C] split h/l
__global__ void k_prepws2(const float* __restrict__ W, int O, int C,
                          unsigned short* __restrict__ WcH, unsigned short* __restrict__ WcL) {
    int i = blockIdx.x * 256 + threadIdx.x;
    if (i >= 2 * O * C) return;
    int r = i / C, k = i % C;
    float v;
    if (r < O) v = W[r * 2 * C + k];
    else {
        int o = r - O;
        v = W[o * 2 * C + C + k] - W[o * 2 * C + k];
    }
    split2(v, WcH[i], WcL[i]);
}

// ---------------- split w5 [1024][512] fp32 -> hi/lo bf16
__global__ void k_splitw5(const float* __restrict__ w5, unsigned short* __restrict__ w5H,
                          unsigned short* __restrict__ w5L) {
    int i = blockIdx.x * 256 + threadIdx.x;
    if (i >= 1024 * 512) return;
    split2(w5[i], w5H[i], w5L[i]);
}

// ---------------- fp32 edge conv (layer 1 only, tiny C)
template <int O, int CP>
__launch_bounds__(O)
__global__ void k_conv(const float* __restrict__ F, int ld, const int* __restrict__ gidx,
                       const float* __restrict__ WaT, const float* __restrict__ WdT,
                       float* __restrict__ hmax, float* __restrict__ s1p,
                       float* __restrict__ s2p) {
    constexpr int CP4 = CP / 4;
    __shared__ float nbrT[2][CP][32];
    __shared__ float sctr[2][CP];
    __shared__ int sidx[2][KK];
    int t = threadIdx.x;
    int p0 = blockIdx.x * 2;
    int b = p0 >> 11;
    const float* Fb = F + (size_t)b * NP * ld;

    if (t < 2 * KK) {
        int pt = t / KK, k = t % KK;
        sidx[pt][k] = gidx[(size_t)(p0 + pt) * KK + k];
    }
    for (int e = t; e < 2 * CP; e += O) {
        int pt = e / CP, cc = e % CP;
        int n = (p0 + pt) & 2047;
        sctr[pt][cc] = Fb[(size_t)n * ld + cc];
    }
    __syncthreads();
    for (int e = t; e < 2 * KK * CP4; e += O) {
        int pt = e / (KK * CP4);
        int e2 = e % (KK * CP4);
        int k = e2 / CP4, cq = e2 % CP4;
        float4 f = *(const float4*)&Fb[(size_t)sidx[pt][k] * ld + cq * 4];
        int kp = (k + 4 * (cq & 7)) & 31;
        nbrT[pt][cq * 4 + 0][kp] = f.x;
        nbrT[pt][cq * 4 + 1][kp] = f.y;
        nbrT[pt][cq * 4 + 2][kp] = f.z;
        nbrT[pt][cq * 4 + 3][kp] = f.w;
    }
    __syncthreads();

    int o = t;
    float bacc0 = 0.f, bacc1 = 0.f;
#pragma unroll 4
    for (int c = 0; c < CP; ++c) {
        float w = WdT[c * O + o];
        bacc0 += sctr[0][c] * w;
        bacc1 += sctr[1][c] * w;
    }
    float a0[KK], a1[KK];
#pragma unroll
    for (int k = 0; k < KK; ++k) { a0[k] = 0.f; a1[k] = 0.f; }
#pragma unroll 2
    for (int c = 0; c < CP; ++c) {
        float w = WaT[c * O + o];
        int s = 4 * ((c >> 2) & 7);
#pragma unroll
        for (int kq = 0; kq < KK / 4; ++kq) {
            int kp = (4 * kq + s) & 31;
            float4 f0 = *(const float4*)&nbrT[0][c][kp];
            float4 f1 = *(const float4*)&nbrT[1][c][kp];
            a0[kq * 4 + 0] += w * f0.x; a1[kq * 4 + 0] += w * f1.x;
            a0[kq * 4 + 1] += w * f0.y; a1[kq * 4 + 1] += w * f1.y;
            a0[kq * 4 + 2] += w * f0.z; a1[kq * 4 + 2] += w * f1.z;
            a0[kq * 4 + 3] += w * f0.w; a1[kq * 4 + 3] += w * f1.w;
        }
    }
    float hm0 = NEG, hm1 = NEG, ts1 = 0.f, ts2 = 0.f;
#pragma unroll
    for (int k = 0; k < KK; ++k) {
        float h0 = a0[k] + bacc0;
        float h1 = a1[k] + bacc1;
        hm0 = fmaxf(hm0, h0); hm1 = fmaxf(hm1, h1);
        ts1 += h0 + h1; ts2 += h0 * h0 + h1 * h1;
    }
    hmax[(size_t)p0 * O + o] = hm0;
    hmax[(size_t)(p0 + 1) * O + o] = hm1;
    int slot = blockIdx.x & (SLOTS - 1);
    atomicAdd(&s1p[slot * O + o], ts1);
    atomicAdd(&s2p[slot * O + o], ts2);
}

// ---------------- dense split GEMM: Gz[BN][O] = hc[:, COFF:COFF+C] @ Wcmb^T (fp32 out)
template <int O, int C, int COFF>
__launch_bounds__(256, 4)
__global__ void k_gemms(const unsigned short* __restrict__ hcH,
                        const unsigned short* __restrict__ hcL,
                        const unsigned short* __restrict__ WdH,
                        const unsigned short* __restrict__ WdL,
                        float* __restrict__ bacc) {
    constexpr int KS = C / 16;
    int tid = threadIdx.x, wave = tid >> 6, lane = tid & 63;
    int row = lane & 31, half = lane >> 5;
    int p0 = blockIdx.x * 128 + wave * 32;
    int ob = blockIdx.y * 64;
    const unsigned short* aH = hcH + (size_t)(p0 + row) * 512 + COFF;
    const unsigned short* aL = hcL + (size_t)(p0 + row) * 512 + COFF;
    f32x16 acc[2];
#pragma unroll
    for (int nt = 0; nt < 2; ++nt)
#pragma unroll
        for (int r = 0; r < 16; ++r) acc[nt][r] = 0.f;

#pragma unroll 2
    for (int ks = 0; ks < KS; ++ks) {
        int k0 = ks * 16 + half * 8;
        bf16x8 avh = *(const bf16x8*)(aH + k0);
        bf16x8 avl = *(const bf16x8*)(aL + k0);
#pragma unroll
        for (int nt = 0; nt < 2; ++nt) {
            int j = ob + nt * 32 + row;
            bf16x8 bvh = *(const bf16x8*)(WdH + (size_t)j * C + k0);
            bf16x8 bvl = *(const bf16x8*)(WdL + (size_t)j * C + k0);
            acc[nt] = __builtin_amdgcn_mfma_f32_32x32x16_bf16(avh, bvh, acc[nt], 0, 0, 0);
            acc[nt] = __builtin_amdgcn_mfma_f32_32x32x16_bf16(avh, bvl, acc[nt], 0, 0, 0);
            acc[nt] = __builtin_amdgcn_mfma_f32_32x32x16_bf16(avl, bvh, acc[nt], 0, 0, 0);
        }
    }
#pragma unroll
    for (int nt = 0; nt < 2; ++nt)
#pragma unroll
        for (int r = 0; r < 16; ++r) {
            int i = (r & 3) + 8 * (r >> 2) + 4 * half;
            bacc[(size_t)(p0 + i) * O + ob + nt * 32 + row] = acc[nt][r];
        }
}

// ---------------- gather-max epilogue: hmax[p,o] = max_k Gz[nbr_k, o] + bacc
template <int O>
__launch_bounds__(256)
__global__ void k_gmax(const float* __restrict__ Gz, const int* __restrict__ gidx,
                       float* __restrict__ hmax, float* __restrict__ s1p,
                       float* __restrict__ s2p) {
    constexpr int PB = 256 / O;      // points per block
    constexpr int O2 = 2 * O;
    __shared__ int sidx[PB][KK];
    int t = threadIdx.x;
    int pt = t / O, o = t % O;
    int p0 = blockIdx.x * PB;
    if (t < PB * KK) sidx[t / KK][t % KK] = gidx[(size_t)(p0 + t / KK) * KK + t % KK];
    __syncthreads();

    int p = p0 + pt;
    int b = p >> 11;
    const float* Gb = Gz + (size_t)b * 2048 * O2;
    float bacc = Gz[(size_t)p * O2 + O + o];
    float mx = NEG, ts1 = 0.f, ts2 = 0.f;
#pragma unroll 5
    for (int k = 0; k < KK; ++k) {
        float g = Gb[(size_t)sidx[pt][k] * O2 + o];
        float h = g + bacc;
        mx = fmaxf(mx, g);
        ts1 += h; ts2 += h * h;
    }
    hmax[(size_t)p * O + o] = mx + bacc;
    int slot = blockIdx.x & (SLOTSM - 1);
    atomicAdd(&s1p[slot * O + o], ts1);
    atomicAdd(&s2p[slot * O + o], ts2);
}

// ---------------- reduce slotted stats -> s1g/s2g
__global__ void k_redslots(const float* __restrict__ s1p, const float* __restrict__ s2p,
                           int O, int S, float* __restrict__ s1g, float* __restrict__ s2g) {
    int o = blockIdx.x * 256 + threadIdx.x;
    if (o >= O) return;
    float a = 0.f, c = 0.f;
    for (int s = 0; s < S; ++s) { a += s1p[s * O + o]; c += s2p[s * O + o]; }
    s1g[o] = a; s2g[o] = c;
}

// ---------------- BN(+leaky) on per-point max; writes split hi/lo bf16
__global__ void k_bnmax(const float* __restrict__ hmax, int O, const float* __restrict__ s1g,
                        const float* __restrict__ s2g, const float* __restrict__ gam,
                        const float* __restrict__ bet, unsigned short* __restrict__ outH,
                        unsigned short* __restrict__ outL, int ostride, int ooff,
                        float inv_cnt) {
    int i = blockIdx.x * 256 + threadIdx.x;
    if (i >= BN * O) return;
    int o = i % O, p = i / O;
    float m = s1g[o] * inv_cnt;
    float v = s2g[o] * inv_cnt - m * m;
    float rs = rsqrtf(v + EPSBN);
    float y = leaky(gam[o] * (hmax[i] - m) * rs + bet[o]);
    size_t oi = (size_t)p * ostride + ooff + o;
    split2(y, outH[oi], outL[oi]);
}

// ---------------- pack: hi/lo bf16 cols [coff+o0,...) -> quad-packed FT4 [CP4][BN]
__global__ void k_pack4(const unsigned short* __restrict__ inH,
                        const unsigned short* __restrict__ inL, int coff,
                        float4* __restrict__ out) {
    __shared__ float tile[64][65];
    int tx = threadIdx.x & 63, ty = threadIdx.x >> 6;
    int p0 = blockIdx.x * 64, o0 = blockIdx.y * 64;
    for (int i = ty; i < 64; i += 4) {
        size_t idx = (size_t)(p0 + i) * 512 + coff + o0 + tx;
        tile[i][tx] = b2f(inH[idx]) + b2f(inL[idx]);
    }
    __syncthreads();
    for (int q = ty; q < 16; q += 4) {
        float4 v;
        v.x = tile[tx][4 * q + 0];
        v.y = tile[tx][4 * q + 1];
        v.z = tile[tx][4 * q + 2];
        v.w = tile[tx][4 * q + 3];
        out[(size_t)(o0 / 4 + q) * BN + p0 + tx] = v;
    }
}

// ---------------- w5 split GEMM: g5 = hc[BN][512] @ w5^T -> fp32 [BN][1024] + stats
// 64 rows/block (two 32-row groups per wave), NT=4 cols tiles, grid = (BN/64, 2).
// Per-row MFMA chain identical to prior rounds -> bit-identical g5.
__launch_bounds__(256, 2)
__global__ void k_w5ms(const unsigned short* __restrict__ hcH,
                       const unsigned short* __restrict__ hcL,
                       const unsigned short* __restrict__ w5H,
                       const unsigned short* __restrict__ w5L,
                       float* __restrict__ g5, float* __restrict__ s1p,
                       float* __restrict__ s2p) {
    int tid = threadIdx.x, wave = tid >> 6, lane = tid & 63;
    int row = lane & 31, half = lane >> 5;
    int p0 = blockIdx.x * 64;
    int ob = blockIdx.y * 512 + wave * 128;
    const unsigned short* aH0 = hcH + (size_t)(p0 + row) * 512;
    const unsigned short* aL0 = hcL + (size_t)(p0 + row) * 512;
    const unsigned short* aH1 = hcH + (size_t)(p0 + 32 + row) * 512;
    const unsigned short* aL1 = hcL + (size_t)(p0 + 32 + row) * 512;
    f32x16 acc0[4], acc1[4];
#pragma unroll
    for (int nt = 0; nt < 4; ++nt)
#pragma unroll
        for (int r = 0; r < 16; ++r) { acc0[nt][r] = 0.f; acc1[nt][r] = 0.f; }

#pragma unroll 2
    for (int ks = 0; ks < 32; ++ks) {
        int k0 = ks * 16 + half * 8;
        bf16x8 avh0 = *(const bf16x8*)(aH0 + k0);
        bf16x8 avl0 = *(const bf16x8*)(aL0 + k0);
        bf16x8 avh1 = *(const bf16x8*)(aH1 + k0);
        bf16x8 avl1 = *(const bf16x8*)(aL1 + k0);
#pragma unroll
        for (int nt = 0; nt < 4; ++nt) {
            int j = ob + nt * 32 + row;
            bf16x8 bvh = *(const bf16x8*)(w5H + (size_t)j * 512 + k0);
            bf16x8 bvl = *(const bf16x8*)(w5L + (size_t)j * 512 + k0);
            acc0[nt] = __builtin_amdgcn_mfma_f32_32x32x16_bf16(avh0, bvh, acc0[nt], 0, 0, 0);
            acc0[nt] = __builtin_amdgcn_mfma_f32_32x32x16_bf16(avh0, bvl, acc0[nt], 0, 0, 0);
            acc0[nt] = __builtin_amdgcn_mfma_f32_32x32x16_bf16(avl0, bvh, acc0[nt], 0, 0, 0);
            acc1[nt] = __builtin_amdgcn_mfma_f32_32x32x16_bf16(avh1, bvh, acc1[nt], 0, 0, 0);
            acc1[nt] = __builtin_amdgcn_mfma_f32_32x32x16_bf16(avh1, bvl, acc1[nt], 0, 0, 0);
            acc1[nt] = __builtin_amdgcn_mfma_f32_32x32x16_bf16(avl1, bvh, acc1[nt], 0, 0, 0);
        }
    }
    int slot = blockIdx.x & (SLOTSW - 1);
#pragma unroll
    for (int nt = 0; nt < 4; ++nt) {
        int j = ob + nt * 32 + row;
        float s10 = 0.f, s20 = 0.f, s11 = 0.f, s21 = 0.f;
#pragma unroll
        for (int r = 0; r < 16; ++r) {
            int i = (r & 3) + 8 * (r >> 2) + 4 * half;
            float v0 = acc0[nt][r];
            float v1 = acc1[nt][r];
            g5[(size_t)(p0 + i) * 1024 + j] = v0;
            g5[(size_t)(p0 + 32 + i) * 1024 + j] = v1;
            s10 += v0; s20 += v0 * v0;
            s11 += v1; s21 += v1 * v1;
        }
        s10 += __shfl_xor(s10, 32);
        s20 += __shfl_xor(s20, 32);
        s11 += __shfl_xor(s11, 32);
        s21 += __shfl_xor(s21, 32);
        if (half == 0) {
            atomicAdd(&s1p[slot * 1024 + j], s10 + s11);
            atomicAdd(&s2p[slot * 1024 + j], s20 + s21);
        }
    }
}

// ---------------- pool: per (b, o-tile, n-chunk) partial max / partial sum
__global__ void k_pool(const float* __restrict__ gbuf, const float* __restrict__ s1g,
                       const float* __restrict__ s2g, const float* __restrict__ gam,
                       const float* __restrict__ bet, float* __restrict__ pmax,
                       float* __restrict__ psum) {
    int t = threadIdx.x;
    int blk = blockIdx.x;
    int nc = blk & 7, ot = (blk >> 3) & 3, b = blk >> 5;
    int o = ot * 256 + t;
    float m = s1g[o] * (1.f / 16384.f);
    float v = s2g[o] * (1.f / 16384.f) - m * m;
    float rs = rsqrtf(v + EPSBN);
    float ga = gam[o], be = bet[o];
    float vmax = NEG, vsum = 0.f;
    for (int j = 0; j < 256; ++j) {
        int n = nc * 256 + j;
        float x = gbuf[((size_t)b * NP + n) * 1024 + o];
        float y = leaky(ga * (x - m) * rs + be);
        vmax = fmaxf(vmax, y);
        vsum += y;
    }
    pmax[(b * 1024 + o) * 8 + nc] = vmax;
    psum[(b * 1024 + o) * 8 + nc] = vsum;
}

__global__ void k_poolfin(const float* __restrict__ pmax, const float* __restrict__ psum,
                          float* __restrict__ pooled) {
    int i = blockIdx.x * 256 + threadIdx.x;
    if (i >= 8192) return;
    float mx = NEG, sm = 0.f;
    for (int j = 0; j < 8; ++j) {
        mx = fmaxf(mx, pmax[i * 8 + j]);
        sm += psum[i * 8 + j];
    }
    int b = i >> 10, o = i & 1023;
    pooled[b * 2048 + o] = mx;
    pooled[b * 2048 + 1024 + o] = sm * (1.f / 2048.f);
}

// ---------------- small FC: z[b][o] = in[b] . W[o] (+bias)
template <int CIN>
__global__ void k_fc(const float* __restrict__ in, const float* __restrict__ W,
                     const float* __restrict__ bias, int O, float* __restrict__ z) {
    int i = blockIdx.x * 256 + threadIdx.x;
    if (i >= NB * O) return;
    int b = i / O, o = i % O;
    const float* wr = W + (size_t)o * CIN;
    const float* ir = in + (size_t)b * CIN;
    float acc = 0.f;
#pragma unroll 4
    for (int cq = 0; cq < CIN / 4; ++cq) {
        float4 wv = *(const float4*)&wr[cq * 4];
        float4 iv = *(const float4*)&ir[cq * 4];
        acc += wv.x * iv.x + wv.y * iv.y + wv.z * iv.z + wv.w * iv.w;
    }
    z[i] = acc + (bias ? bias[o] : 0.f);
}

// ---------------- BN over batch (8 samples) + leaky
__global__ void k_bnb(const float* __restrict__ z, int O, const float* __restrict__ gam,
                      const float* __restrict__ bet, float* __restrict__ out, int ostride,
                      int ooff) {
    int o = blockIdx.x * 256 + threadIdx.x;
    if (o >= O) return;
    float s1 = 0.f, s2 = 0.f;
#pragma unroll
    for (int b = 0; b < NB; ++b) {
        float x = z[b * O + o];
        s1 += x; s2 += x * x;
    }
    float m = s1 * 0.125f, v = s2 * 0.125f - m * m;
    float rs = rsqrtf(v + EPSBN);
    float ga = gam[o], be = bet[o];
    for (int b = 0; b < NB; ++b) {
        float y = ga * (z[b * O + o] - m) * rs + be;
        out[b * ostride + ooff + o] = leaky(y);
    }
}

// ---------------- head
__global__ void k_head(const float* __restrict__ hf, const float* __restrict__ wh,
                       const float* __restrict__ bh, const float* __restrict__ g8,
                       const float* __restrict__ b8, float* __restrict__ out) {
    __shared__ float zh[56];
    int t = threadIdx.x;
    if (t < 56) {
        int b = t / 7, o = t % 7;
        float acc = bh[o];
        for (int c = 0; c < 768; ++c) acc += hf[b * 768 + c] * wh[o * 768 + c];
        zh[t] = acc;
    }
    __syncthreads();
    if (t < 7) {
        float s1 = 0.f, s2 = 0.f;
        for (int b = 0; b < NB; ++b) {
            float x = zh[b * 7 + t];
            s1 += x; s2 += x * x;
        }
        float m = s1 * 0.125f, v = s2 * 0.125f - m * m;
        float rs = rsqrtf(v + EPSBN);
        for (int b = 0; b < NB; ++b) {
            float y = g8[t] * (zh[b * 7 + t] - m) * rs + b8[t];
            out[b * 7 + t] = fmaxf(y, 0.f);
        }
    }
}

extern "C" void kernel_launch(void* const* d_in, const int* in_sizes, int n_in, void* d_out,
                              int out_size, void* d_ws, size_t ws_size, hipStream_t stream) {
    const float* x[3] = {(const float*)d_in[0], (const float*)d_in[1], (const float*)d_in[2]};
    const float* w1 = (const float*)d_in[3];
    const float* w2 = (const float*)d_in[4];
    const float* w3 = (const float*)d_in[5];
    const float* w4 = (const float*)d_in[6];
    const float* w5 = (const float*)d_in[7];
    const float* wl1 = (const float*)d_in[8];
    const float* wl2 = (const float*)d_in[9];
    const float* bl2 = (const float*)d_in[10];
    const float* whead = (const float*)d_in[11];
    const float* bhead = (const float*)d_in[12];
    const float *g1 = (const float*)d_in[13], *b1 = (const float*)d_in[14];
    const float *g2 = (const float*)d_in[15], *b2 = (const float*)d_in[16];
    const float *g3 = (const float*)d_in[17], *b3 = (const float*)d_in[18];
    const float *g4 = (const float*)d_in[19], *b4 = (const float*)d_in[20];
    const float *g5 = (const float*)d_in[21], *b5 = (const float*)d_in[22];
    const float *g6 = (const float*)d_in[23], *b6 = (const float*)d_in[24];
    const float *g7 = (const float*)d_in[25], *b7 = (const float*)d_in[26];
    const float *g8 = (const float*)d_in[27], *b8 = (const float*)d_in[28];

    char* w = (char*)d_ws;
    auto alloc = [&](size_t bytes) {
        char* p = w;
        w += (bytes + 255) & ~(size_t)255;
        return p;
    };
    float* xt   = (float*)alloc((size_t)BN * 4 * 4);
    unsigned short* hcH = (unsigned short*)alloc((size_t)BN * 512 * 2);
    unsigned short* hcL = (unsigned short*)alloc((size_t)BN * 512 * 2);
    float4* ft4 = (float4*)alloc((size_t)32 * BN * 16);   // quad-packed knn features
    float* gbig = (float*)alloc((size_t)BN * 1024 * 4);  // Gz[0,BN*512) | hmax@BN*512 | g5 full
    int*   idx  = (int*)alloc((size_t)BN * KK * 4);
    float* sqv  = (float*)alloc((size_t)BN * 4);
    float* s1g  = (float*)alloc(1024 * 4);
    float* s2g  = (float*)alloc(1024 * 4);
    float* spart  = (float*)alloc(2 * SLOTS * 256 * 4);     // conv1 fp32 stats
    float* spartC = (float*)alloc(2 * SLOTSM * 256 * 4);    // gmax stats
    float* spartW = (float*)alloc(2 * SLOTSW * 1024 * 4);   // w5 stats
    float* pmax = (float*)alloc(8 * 1024 * 8 * 4);
    float* psum = (float*)alloc(8 * 1024 * 8 * 4);
    float* pooled = (float*)alloc(8 * 2048 * 4);
    float* z1 = (float*)alloc(8 * 512 * 4);
    float* a1 = (float*)alloc(8 * 512 * 4);
    float* z2 = (float*)alloc(8 * 256 * 4);
    float* hfeat = (float*)alloc(8 * 768 * 4);
    float* Wa1 = (float*)alloc(4 * 64 * 4);
    float* Wd1 = (float*)alloc(4 * 64 * 4);
    unsigned short* WcH2 = (unsigned short*)alloc(128 * 64 * 2);
    unsigned short* WcL2 = (unsigned short*)alloc(128 * 64 * 2);
    unsigned short* WcH3 = (unsigned short*)alloc(256 * 64 * 2);
    unsigned short* WcL3 = (unsigned short*)alloc(256 * 64 * 2);
    unsigned short* WcH4 = (unsigned short*)alloc(512 * 128 * 2);
    unsigned short* WcL4 = (unsigned short*)alloc(512 * 128 * 2);
    unsigned short* w5H  = (unsigned short*)alloc(1024 * 512 * 2);
    unsigned short* w5L  = (unsigned short*)alloc(1024 * 512 * 2);
    float* s1p = spart;
    float* s2p = spart + SLOTS * 256;
    float* s1pc = spartC;
    float* s2pc = spartC + SLOTSM * 256;
    float* s1pw = spartW;
    float* s2pw = spartW + SLOTSW * 1024;
    float* hmaxP = gbig + (size_t)BN * 512;   // disjoint from Gz region [0, BN*512)

    // weight prep (plane-independent)
    k_prepw<<<(4 * 64 + 255) / 256, 256, 0, stream>>>(w1, 64, 3, 4, Wa1, Wd1);
    k_prepws2<<<(128 * 64 + 255) / 256, 256, 0, stream>>>(w2, 64, 64, WcH2, WcL2);
    k_prepws2<<<(256 * 64 + 255) / 256, 256, 0, stream>>>(w3, 128, 64, WcH3, WcL3);
    k_prepws2<<<(512 * 128 + 255) / 256, 256, 0, stream>>>(w4, 256, 128, WcH4, WcL4);
    k_splitw5<<<(1024 * 512) / 256, 256, 0, stream>>>(w5, w5H, w5L);

    const float inv_e = 1.f / (float)(BN * KK);
    for (int p = 0; p < 3; ++p) {
        k_transpose<<<BN / 256, 256, 0, stream>>>(x[p], xt);

        // ---- layer 1 (fp32): C=3 pad 4, O=64 -> cols 0:64 ; xt doubles as FT4 (CP4=1)
        k_sq4<1><<<BN / 256, 256, 0, stream>>>((const float4*)xt, sqv);
        k_knn2<4><<<NB * (NP / 8), 512, 0, stream>>>((const float4*)xt, sqv, idx);
        hipMemsetAsync(spart, 0, 2 * SLOTS * 256 * 4, stream);
        k_conv<64, 4><<<BN / 2, 64, 0, stream>>>(xt, 4, idx, Wa1, Wd1, hmaxP, s1p, s2p);
        k_redslots<<<1, 256, 0, stream>>>(s1p, s2p, 64, SLOTS, s1g, s2g);
        k_bnmax<<<(BN * 64) / 256, 256, 0, stream>>>(hmaxP, 64, s1g, s2g, g1, b1, hcH, hcL, 512, 0, inv_e);
        k_pack4<<<dim3(BN / 64, 1), 256, 0, stream>>>(hcH, hcL, 0, ft4);

        // ---- layer 2: knn (CP=64 packed) + dense Gz=[G|bacc] (O2=128) + gather-max
        k_sq4<16><<<BN / 256, 256, 0, stream>>>(ft4, sqv);
        k_knn2<64><<<NB * (NP / 8), 512, 0, stream>>>(ft4, sqv, idx);
        k_gemms<128, 64, 0><<<dim3(BN / 128, 2), 256, 0, stream>>>(hcH, hcL, WcH2, WcL2, gbig);
        hipMemsetAsync(spartC, 0, 2 * SLOTSM * 256 * 4, stream);
        k_gmax<64><<<BN / 4, 256, 0, stream>>>(gbig, idx, hmaxP, s1pc, s2pc);
        k_redslots<<<1, 256, 0, stream>>>(s1pc, s2pc, 64, SLOTSM, s1g, s2g);
        k_bnmax<<<(BN * 64) / 256, 256, 0, stream>>>(hmaxP, 64, s1g, s2g, g2, b2, hcH, hcL, 512, 64, inv_e);
        k_pack4<<<dim3(BN / 64, 1), 256, 0, stream>>>(hcH, hcL, 64, ft4);

        // ---- layer 3: O2=256
        k_sq4<16><<<BN / 256, 256, 0, stream>>>(ft4, sqv);
        k_knn2<64><<<NB * (NP / 8), 512, 0, stream>>>(ft4, sqv, idx);
        k_gemms<256, 64, 64><<<dim3(BN / 128, 4), 256, 0, stream>>>(hcH, hcL, WcH3, WcL3, gbig);
        hipMemsetAsync(spartC, 0, 2 * SLOTSM * 256 * 4, stream);
        k_gmax<128><<<BN / 2, 256, 0, stream>>>(gbig, idx, hmaxP, s1pc, s2pc);
        k_redslots<<<1, 256, 0, stream>>>(s1pc, s2pc, 128, SLOTSM, s1g, s2g);
        k_bnmax<<<(BN * 128) / 256, 256, 0, stream>>>(hmaxP, 128, s1g, s2g, g3, b3, hcH, hcL, 512, 128, inv_e);
        k_pack4<<<dim3(BN / 64, 2), 256, 0, stream>>>(hcH, hcL, 128, ft4);

        // ---- layer 4: O2=512
        k_sq4<32><<<BN / 256, 256, 0, stream>>>(ft4, sqv);
        k_knn2<128><<<NB * (NP / 8), 512, 0, stream>>>(ft4, sqv, idx);
        k_gemms<512, 128, 128><<<dim3(BN / 128, 8), 256, 0, stream>>>(hcH, hcL, WcH4, WcL4, gbig);
        hipMemsetAsync(spartC, 0, 2 * SLOTSM * 256 * 4, stream);
        k_gmax<256><<<BN, 256, 0, stream>>>(gbig, idx, hmaxP, s1pc, s2pc);
        k_redslots<<<1, 256, 0, stream>>>(s1pc, s2pc, 256, SLOTSM, s1g, s2g);
        k_bnmax<<<(BN * 256) / 256, 256, 0, stream>>>(hmaxP, 256, s1g, s2g, g4, b4, hcH, hcL, 512, 256, inv_e);

        // ---- w5 (mfma split, 64 rows x NT=4) + BN + pool
        hipMemsetAsync(spartW, 0, 2 * SLOTSW * 1024 * 4, stream);
        k_w5ms<<<dim3(BN / 64, 2), 256, 0, stream>>>(hcH, hcL, w5H, w5L, gbig, s1pw, s2pw);
        k_redslots<<<4, 256, 0, stream>>>(s1pw, s2pw, 1024, SLOTSW, s1g, s2g);
        k_pool<<<256, 256, 0, stream>>>(gbig, s1g, s2g, g5, b5, pmax, psum);
        k_poolfin<<<32, 256, 0, stream>>>(pmax, psum, pooled);

        // ---- FC head of the plane
        k_fc<2048><<<(8 * 512 + 255) / 256, 256, 0, stream>>>(pooled, wl1, nullptr, 512, z1);
        k_bnb<<<2, 256, 0, stream>>>(z1, 512, g6, b6, a1, 512, 0);
        k_fc<512><<<(8 * 256 + 255) / 256, 256, 0, stream>>>(a1, wl2, bl2, 256, z2);
        k_bnb<<<1, 256, 0, stream>>>(z2, 256, g7, b7, hfeat, 768, p * 256);
    }
    k_head<<<1, 64, 0, stream>>>(hfeat, whead, bhead, g8, b8, (float*)d_out);
}